// Round 1
// baseline (4211.785 us; speedup 1.0000x reference)
//
#include <hip/hip_runtime.h>
#include <hip/hip_bf16.h>

#define N_NODES 50000
#define N_EDGES 500000
#define DIM 128

typedef __bf16 bf16_t;
typedef __bf16 bf16x8 __attribute__((ext_vector_type(8)));
typedef float f32x4 __attribute__((ext_vector_type(4)));

#define MFMA(a,b,c) __builtin_amdgcn_mfma_f32_16x16x32_bf16((a),(b),(c),0,0,0)

// XOR swizzle (guide G4): kills 32-way bank conflicts for 256B/512B-stride rows
__device__ __forceinline__ int swz(int row, int kbyte){ return kbyte ^ ((row & 7) << 4); }

__device__ __forceinline__ bf16x8 lds_frag(const char* s, int row, int rowb, int kbyte){
  return *(const bf16x8*)(s + row * rowb + swz(row, kbyte));
}

__device__ __forceinline__ void copy16(char* dst, const char* __restrict__ src, int bytes){
  for (int o = threadIdx.x * 16; o < bytes; o += blockDim.x * 16)
    *(f32x4*)(dst + o) = *(const f32x4*)(src + o);
}

// ---------------- weight prep: f32 [K][N] -> bf16 transposed swizzled image [n][k] ----------------
struct WPrep {
  const float* w[10];
  int Kd[10], Nd[10], off[10], cum[10];
};

__global__ void k_wprep(WPrep d, char* img, int total){
  for (int idx = blockIdx.x * blockDim.x + threadIdx.x; idx < total; idx += gridDim.x * blockDim.x){
    int i = 0;
#pragma unroll
    for (int j = 1; j < 10; j++) if (idx >= d.cum[j]) i = j;
    int loc = idx - d.cum[i];
    int K = d.Kd[i], N = d.Nd[i];
    int n = loc / K, k = loc - n * K;
    float val = d.w[i][(size_t)k * N + n];
    *(bf16_t*)(img + d.off[i] + n * (K * 2) + swz(n, k * 2)) = (bf16_t)val;
  }
}

// ---------------- QKV: [M,128] @ 3x [128,128] ----------------
__global__ __launch_bounds__(512) void k_qkv(
    const float* __restrict__ v, const char* __restrict__ img,
    float* __restrict__ Q, float* __restrict__ K, float* __restrict__ V, int M)
{
  __shared__ __align__(16) char sm[131072];
  char* sX = sm;
  char* sW = sm + 32768;
  const int tid = threadIdx.x, lane = tid & 63, wave = tid >> 6;
  const int r0 = blockIdx.x * 128;
  copy16(sW, img, 98304);
  for (int c = tid; c < 2048; c += 512){
    int row = c >> 4, kc = c & 15, grow = r0 + row;
    float f[8];
    if (grow < M){
      const float4* p = (const float4*)(v + (size_t)grow * DIM + kc * 8);
      float4 u0 = p[0], u1 = p[1];
      f[0]=u0.x; f[1]=u0.y; f[2]=u0.z; f[3]=u0.w;
      f[4]=u1.x; f[5]=u1.y; f[6]=u1.z; f[7]=u1.w;
    } else {
#pragma unroll
      for (int j=0;j<8;j++) f[j] = 0.f;
    }
    bf16x8 o;
#pragma unroll
    for (int j=0;j<8;j++) o[j] = (bf16_t)f[j];
    *(bf16x8*)(sX + row * 256 + swz(row, kc * 16)) = o;
  }
  __syncthreads();
  const int rowA = wave * 16 + (lane & 15);
  const int kb0 = (lane >> 4) * 16;
  const f32x4 zero4 = {0.f, 0.f, 0.f, 0.f};
  f32x4 acc[3][8];
#pragma unroll
  for (int a=0;a<3;a++)
#pragma unroll
    for (int b=0;b<8;b++) acc[a][b] = zero4;
#pragma unroll
  for (int ks=0; ks<4; ks++){
    bf16x8 a = lds_frag(sX, rowA, 256, ks*64 + kb0);
#pragma unroll
    for (int w3=0; w3<3; w3++)
#pragma unroll
      for (int nt=0; nt<8; nt++){
        int rn = nt*16 + (lane & 15);
        bf16x8 b = lds_frag(sW + w3*32768, rn, 256, ks*64 + kb0);
        acc[w3][nt] = MFMA(a, b, acc[w3][nt]);
      }
  }
  const int crow = wave*16 + (lane >> 4)*4;
  const int ccol = lane & 15;
#pragma unroll
  for (int w3=0; w3<3; w3++){
    float* o = (w3 == 0) ? Q : ((w3 == 1) ? K : V);
#pragma unroll
    for (int nt=0; nt<8; nt++)
#pragma unroll
      for (int r=0; r<4; r++){
        int grow = r0 + crow + r;
        if (grow < M) o[(size_t)grow * DIM + nt*16 + ccol] = acc[w3][nt][r];
      }
  }
}

// ---------------- fused edge attention ----------------
// pe = e@We; score = K[src]*Q[dst]*pe/4; s = exp(clip(head-sums)); e1_pre = e + score@WO_e + bOe
// scatter: wV[dst] += V[src]*env*s ; z[dst] += s ; BN1e stats
__global__ __launch_bounds__(512) void k_edge(
    const float* __restrict__ e, const float* __restrict__ envl,
    const int* __restrict__ src, const int* __restrict__ dst,
    const float* __restrict__ Q, const float* __restrict__ K, const float* __restrict__ V,
    const char* __restrict__ imgWe, const char* __restrict__ imgWo,
    const float* __restrict__ bOe,
    float* __restrict__ e1_pre, float* __restrict__ wV, float* __restrict__ z,
    float* __restrict__ stats, int M)
{
  __shared__ __align__(16) char sm[104960];
  char* sWe = sm;
  char* sWo = sm + 32768;
  char* sX  = sm + 65536;            // e tile (bf16), later score (bf16)
  float* sS     = (float*)(sm + 98304);   // [128][8] per-head s
  float* sStats = (float*)(sm + 102400);  // [256]
  int*   sSrc   = (int*)(sm + 103424);
  int*   sDst   = (int*)(sm + 103936);
  float* sEnv   = (float*)(sm + 104448);
  const int tid = threadIdx.x, lane = tid & 63, wave = tid >> 6;
  const int r0 = blockIdx.x * 128;
  copy16(sWe, imgWe, 32768);
  copy16(sWo, imgWo, 32768);
  if (tid < 128){
    int ed = r0 + tid;
    sSrc[tid] = (ed < M) ? src[ed] : 0;
    sDst[tid] = (ed < M) ? dst[ed] : 0;
    sEnv[tid] = (ed < M) ? envl[ed] : 0.f;
  }
  if (tid < 256) sStats[tid] = 0.f;
  for (int c = tid; c < 2048; c += 512){
    int row = c >> 4, kc = c & 15, grow = r0 + row;
    float f[8];
    if (grow < M){
      const float4* p = (const float4*)(e + (size_t)grow * DIM + kc * 8);
      float4 u0 = p[0], u1 = p[1];
      f[0]=u0.x; f[1]=u0.y; f[2]=u0.z; f[3]=u0.w;
      f[4]=u1.x; f[5]=u1.y; f[6]=u1.z; f[7]=u1.w;
    } else {
#pragma unroll
      for (int j=0;j<8;j++) f[j] = 0.f;
    }
    bf16x8 o;
#pragma unroll
    for (int j=0;j<8;j++) o[j] = (bf16_t)f[j];
    *(bf16x8*)(sX + row * 256 + swz(row, kc * 16)) = o;
  }
  __syncthreads();
  const int rowA = wave * 16 + (lane & 15);
  const int kb0 = (lane >> 4) * 16;
  const f32x4 zero4 = {0.f,0.f,0.f,0.f};
  f32x4 pe[8];
#pragma unroll
  for (int i=0;i<8;i++) pe[i] = zero4;
#pragma unroll
  for (int ks=0; ks<4; ks++){
    bf16x8 a = lds_frag(sX, rowA, 256, ks*64 + kb0);
#pragma unroll
    for (int nt=0; nt<8; nt++){
      int rn = nt*16 + (lane & 15);
      bf16x8 b = lds_frag(sWe, rn, 256, ks*64 + kb0);
      pe[nt] = MFMA(a, b, pe[nt]);
    }
  }
  __syncthreads();   // done reading e-tile; sX will be reused for score
  const int crow = wave*16 + (lane >> 4)*4;
  const int ccol = lane & 15;
  const float* Kb[4]; const float* Qb[4];
#pragma unroll
  for (int r=0;r<4;r++){
    int row = crow + r;
    Kb[r] = K + (size_t)sSrc[row] * DIM;
    Qb[r] = Q + (size_t)sDst[row] * DIM;
  }
  float sc[8][4];
#pragma unroll
  for (int nt=0; nt<8; nt++)
#pragma unroll
    for (int r=0;r<4;r++){
      int col = nt*16 + ccol;
      sc[nt][r] = pe[nt][r] * 0.25f * Kb[r][col] * Qb[r][col];
    }
  // write score (bf16) to sX for GEMM2; head-sum -> s (head == 16-col n-tile)
#pragma unroll
  for (int nt=0; nt<8; nt++)
#pragma unroll
    for (int r=0;r<4;r++){
      int row = crow + r, col = nt*16 + ccol;
      *(bf16_t*)(sX + row*256 + swz(row, col*2)) = (bf16_t)sc[nt][r];
      float hv = sc[nt][r];
      hv += __shfl_xor(hv, 1);
      hv += __shfl_xor(hv, 2);
      hv += __shfl_xor(hv, 4);
      hv += __shfl_xor(hv, 8);
      if (ccol == 0)
        sS[row*8 + nt] = expf(fminf(5.f, fmaxf(-5.f, hv)));
    }
  __syncthreads();
  // GEMM2: e_attn @ WO_e
  f32x4 a2[8];
#pragma unroll
  for (int i=0;i<8;i++) a2[i] = zero4;
#pragma unroll
  for (int ks=0; ks<4; ks++){
    bf16x8 a = lds_frag(sX, rowA, 256, ks*64 + kb0);
#pragma unroll
    for (int nt=0; nt<8; nt++){
      int rn = nt*16 + (lane & 15);
      bf16x8 b = lds_frag(sWo, rn, 256, ks*64 + kb0);
      a2[nt] = MFMA(a, b, a2[nt]);
    }
  }
  // scatter messages (4 threads per edge row, 32 cols each)
  {
    int row = tid & 127, quarter = tid >> 7;
    int ed = r0 + row;
    if (ed < M){
      int sn = sSrc[row], dn = sDst[row];
      float env = sEnv[row];
      const float* Vb = V + (size_t)sn * DIM;
      float* Wb = wV + (size_t)dn * DIM;
#pragma unroll
      for (int j=0; j<32; j++){
        int c = quarter*32 + j;
        float sval = sS[row*8 + (c >> 4)];
        unsafeAtomicAdd(&Wb[c], Vb[c] * env * sval);
      }
      if (quarter == 0){
#pragma unroll
        for (int h=0; h<8; h++)
          unsafeAtomicAdd(&z[(size_t)dn*8 + h], sS[row*8 + h]);
      }
    }
  }
  // epilogue: e1_pre = e + attn_out + bOe ; BN stats
#pragma unroll
  for (int nt=0; nt<8; nt++){
    float s1 = 0.f, s2 = 0.f;
#pragma unroll
    for (int r=0; r<4; r++){
      int row = crow + r, col = nt*16 + ccol;
      int ed = r0 + row;
      float val = 0.f;
      if (ed < M){
        val = a2[nt][r] + e[(size_t)ed * DIM + col] + bOe[col];
        e1_pre[(size_t)ed * DIM + col] = val;
      }
      s1 += val; s2 += val * val;
    }
    s1 += __shfl_xor(s1, 16); s1 += __shfl_xor(s1, 32);
    s2 += __shfl_xor(s2, 16); s2 += __shfl_xor(s2, 32);
    if (lane < 16){
      atomicAdd(&sStats[nt*16 + ccol], s1);
      atomicAdd(&sStats[128 + nt*16 + ccol], s2);
    }
  }
  __syncthreads();
  if (tid < 256) unsafeAtomicAdd(&stats[tid], sStats[tid]);
}

// ---------------- node: v_attn = wV/(z+eps); v1_pre = v + v_attn@WO_v + bOv; stats ----------------
__global__ __launch_bounds__(512) void k_nodeout(
    const float* __restrict__ wV, const float* __restrict__ z, const float* __restrict__ v,
    const char* __restrict__ imgWo, const float* __restrict__ bOv,
    float* __restrict__ v1_pre, float* __restrict__ stats, int M)
{
  __shared__ __align__(16) char sm[66560];
  char* sW = sm;
  char* sX = sm + 32768;
  float* sStats = (float*)(sm + 65536);
  const int tid = threadIdx.x, lane = tid & 63, wave = tid >> 6;
  const int r0 = blockIdx.x * 128;
  copy16(sW, imgWo, 32768);
  if (tid < 256) sStats[tid] = 0.f;
  for (int c = tid; c < 2048; c += 512){
    int row = c >> 4, kc = c & 15, grow = r0 + row;
    float f[8];
    if (grow < M){
      const float4* p = (const float4*)(wV + (size_t)grow * DIM + kc * 8);
      float4 u0 = p[0], u1 = p[1];
      float inv = 1.f / (z[(size_t)grow*8 + (kc >> 1)] + 1e-6f);
      f[0]=u0.x*inv; f[1]=u0.y*inv; f[2]=u0.z*inv; f[3]=u0.w*inv;
      f[4]=u1.x*inv; f[5]=u1.y*inv; f[6]=u1.z*inv; f[7]=u1.w*inv;
    } else {
#pragma unroll
      for (int j=0;j<8;j++) f[j]=0.f;
    }
    bf16x8 o;
#pragma unroll
    for (int j=0;j<8;j++) o[j]=(bf16_t)f[j];
    *(bf16x8*)(sX + row*256 + swz(row, kc*16)) = o;
  }
  __syncthreads();
  const int rowA = wave*16 + (lane & 15);
  const int kb0 = (lane >> 4)*16;
  const f32x4 zero4 = {0.f,0.f,0.f,0.f};
  f32x4 acc[8];
#pragma unroll
  for (int i=0;i<8;i++) acc[i]=zero4;
#pragma unroll
  for (int ks=0;ks<4;ks++){
    bf16x8 a = lds_frag(sX, rowA, 256, ks*64+kb0);
#pragma unroll
    for (int nt=0;nt<8;nt++){
      int rn = nt*16 + (lane&15);
      bf16x8 b = lds_frag(sW, rn, 256, ks*64+kb0);
      acc[nt] = MFMA(a,b,acc[nt]);
    }
  }
  const int crow = wave*16 + (lane>>4)*4;
  const int ccol = lane & 15;
#pragma unroll
  for (int nt=0;nt<8;nt++){
    float s1=0.f, s2=0.f;
#pragma unroll
    for (int r=0;r<4;r++){
      int grow = r0 + crow + r, col = nt*16 + ccol;
      float val = 0.f;
      if (grow < M){
        val = acc[nt][r] + v[(size_t)grow*DIM + col] + bOv[col];
        v1_pre[(size_t)grow*DIM + col] = val;
      }
      s1 += val; s2 += val*val;
    }
    s1 += __shfl_xor(s1,16); s1 += __shfl_xor(s1,32);
    s2 += __shfl_xor(s2,16); s2 += __shfl_xor(s2,32);
    if (lane < 16){
      atomicAdd(&sStats[nt*16+ccol], s1);
      atomicAdd(&sStats[128+nt*16+ccol], s2);
    }
  }
  __syncthreads();
  if (tid < 256) unsafeAtomicAdd(&stats[tid], sStats[tid]);
}

// ---------------- fused FFN: x1=BN(x_pre); out = x1 + relu(x1@W1+b1)@W2 + b2 (in place); stats ----------------
__global__ __launch_bounds__(512) void k_ffn(
    float* __restrict__ xio, const float* __restrict__ ss1,
    const char* __restrict__ img1, const float* __restrict__ b1,
    const char* __restrict__ img2, const float* __restrict__ b2,
    float* __restrict__ stats2, int M)
{
  __shared__ __align__(16) char sm[132096];
  char* sW  = sm;           // [0,64K): W1 image, then h (128x256 bf16)
  char* sA  = sm + 65536;   // x tile (32K); later W2 image (64K)
  float* sStats = (float*)(sm + 131072);
  const int tid = threadIdx.x, lane = tid & 63, wave = tid >> 6;
  const int r0 = blockIdx.x * 128;
  copy16(sW, img1, 65536);
  if (tid < 256) sStats[tid] = 0.f;
  for (int c = tid; c < 2048; c += 512){
    int row = c >> 4, kc = c & 15, grow = r0 + row;
    float f[8];
    if (grow < M){
      const float4* p = (const float4*)(xio + (size_t)grow*DIM + kc*8);
      float4 u0 = p[0], u1 = p[1];
      f[0]=u0.x; f[1]=u0.y; f[2]=u0.z; f[3]=u0.w;
      f[4]=u1.x; f[5]=u1.y; f[6]=u1.z; f[7]=u1.w;
#pragma unroll
      for (int j=0;j<8;j++){ int col = kc*8 + j; f[j] = f[j]*ss1[col] + ss1[128+col]; }
    } else {
#pragma unroll
      for (int j=0;j<8;j++) f[j]=0.f;
    }
    bf16x8 o;
#pragma unroll
    for (int j=0;j<8;j++) o[j]=(bf16_t)f[j];
    *(bf16x8*)(sA + row*256 + swz(row, kc*16)) = o;
  }
  __syncthreads();
  const int rowA = wave*16 + (lane & 15);
  const int kb0 = (lane >> 4) * 16;
  const f32x4 zero4 = {0.f,0.f,0.f,0.f};
  f32x4 h[16];
#pragma unroll
  for (int i=0;i<16;i++) h[i]=zero4;
#pragma unroll
  for (int ks=0;ks<4;ks++){
    bf16x8 a = lds_frag(sA, rowA, 256, ks*64+kb0);
#pragma unroll
    for (int nt=0;nt<16;nt++){
      int rn = nt*16 + (lane&15);
      bf16x8 b = lds_frag(sW, rn, 256, ks*64+kb0);
      h[nt] = MFMA(a,b,h[nt]);
    }
  }
  __syncthreads();  // done with W1 image and x tile
  const int crow = wave*16 + (lane>>4)*4;
  const int ccol = lane & 15;
#pragma unroll
  for (int nt=0;nt<16;nt++)
#pragma unroll
    for (int r=0;r<4;r++){
      int row = crow + r, col = nt*16 + ccol;
      float hv = fmaxf(h[nt][r] + b1[col], 0.f);
      *(bf16_t*)(sW + row*512 + swz(row, col*2)) = (bf16_t)hv;
    }
  copy16(sA, img2, 65536);
  __syncthreads();
  f32x4 o2[8];
#pragma unroll
  for (int i=0;i<8;i++) o2[i]=zero4;
#pragma unroll
  for (int ks=0;ks<8;ks++){
    bf16x8 a = lds_frag(sW, rowA, 512, ks*64+kb0);
#pragma unroll
    for (int nt=0;nt<8;nt++){
      int rn = nt*16 + (lane&15);
      bf16x8 b = lds_frag(sA, rn, 512, ks*64+kb0);
      o2[nt] = MFMA(a,b,o2[nt]);
    }
  }
#pragma unroll
  for (int nt=0;nt<8;nt++){
    float s1=0.f, s2=0.f;
#pragma unroll
    for (int r=0;r<4;r++){
      int row = crow + r, col = nt*16 + ccol;
      int grow = r0 + row;
      float val = 0.f;
      if (grow < M){
        float xp = xio[(size_t)grow*DIM + col];
        float x1 = xp*ss1[col] + ss1[128+col];
        val = x1 + o2[nt][r] + b2[col];
        xio[(size_t)grow*DIM + col] = val;
      }
      s1 += val; s2 += val*val;
    }
    s1 += __shfl_xor(s1,16); s1 += __shfl_xor(s1,32);
    s2 += __shfl_xor(s2,16); s2 += __shfl_xor(s2,32);
    if (lane < 16){
      atomicAdd(&sStats[nt*16+ccol], s1);
      atomicAdd(&sStats[128+nt*16+ccol], s2);
    }
  }
  __syncthreads();
  if (tid < 256) unsafeAtomicAdd(&stats2[tid], sStats[tid]);
}

// ---------------- stats -> scale/shift ----------------
struct FinArgs { const float* st; const float* g; const float* b; float* ss; float invM; };

__global__ void k_finstats(FinArgs a0, FinArgs a1){
  FinArgs a = (blockIdx.x == 0) ? a0 : a1;
  int c = threadIdx.x;
  float mean = a.st[c] * a.invM;
  float var  = a.st[128 + c] * a.invM - mean * mean;
  float scl  = a.g[c] * rsqrtf(var + 1e-5f);
  a.ss[c] = scl;
  a.ss[128 + c] = a.b[c] - mean * scl;
}

// ---------------- in-place normalize ----------------
__global__ void k_norm(float* __restrict__ x, const float* __restrict__ ss, long long n4){
  for (long long i = (long long)blockIdx.x * blockDim.x + threadIdx.x; i < n4;
       i += (long long)gridDim.x * blockDim.x){
    float4* p = (float4*)x + i;
    float4 t = *p;
    int c0 = (int)((i * 4) & 127);
    t.x = t.x * ss[c0]     + ss[128 + c0];
    t.y = t.y * ss[c0 + 1] + ss[128 + c0 + 1];
    t.z = t.z * ss[c0 + 2] + ss[128 + c0 + 2];
    t.w = t.w * ss[c0 + 3] + ss[128 + c0 + 3];
    *p = t;
  }
}

extern "C" void kernel_launch(void* const* d_in, const int* in_sizes, int n_in,
                              void* d_out, int out_size, void* d_ws, size_t ws_size,
                              hipStream_t stream)
{
  const float* v    = (const float*)d_in[0];
  const float* e    = (const float*)d_in[1];
  const float* envl = (const float*)d_in[2];
  const int*   src  = (const int*)d_in[3];
  const int*   dst  = (const int*)d_in[4];
  const float* bOv  = (const float*)d_in[10];
  const float* bOe  = (const float*)d_in[12];
  const float* g1v  = (const float*)d_in[13];
  const float* b1vn = (const float*)d_in[14];
  const float* g1e  = (const float*)d_in[15];
  const float* b1en = (const float*)d_in[16];
  const float* g2v  = (const float*)d_in[17];
  const float* b2vn = (const float*)d_in[18];
  const float* g2e  = (const float*)d_in[19];
  const float* b2en = (const float*)d_in[20];
  const float* b1vf = (const float*)d_in[22];
  const float* b2vf = (const float*)d_in[24];
  const float* b1ef = (const float*)d_in[26];
  const float* b2ef = (const float*)d_in[28];

  float* out_v = (float*)d_out;
  float* out_e = out_v + (size_t)N_NODES * DIM;

  char* ws = (char*)d_ws;
  const size_t IMG_OFF = 0;                       // 458752 B of bf16 weight images
  const size_t Q_OFF   = 458752;
  const size_t K_OFF   = Q_OFF + 25600000;
  const size_t V_OFF   = K_OFF + 25600000;
  const size_t WV_OFF  = V_OFF + 25600000;
  const size_t Z_OFF   = WV_OFF + 25600000;
  const size_t ST_OFF  = Z_OFF + 1600000;
  const size_t SS_OFF  = ST_OFF + 4096;

  char*  img = ws + IMG_OFF;
  float* Qp  = (float*)(ws + Q_OFF);
  float* Kp  = (float*)(ws + K_OFF);
  float* Vp  = (float*)(ws + V_OFF);
  float* wVp = (float*)(ws + WV_OFF);
  float* zp  = (float*)(ws + Z_OFF);
  float* st  = (float*)(ws + ST_OFF);
  float* ssb = (float*)(ws + SS_OFF);
  float* st_e1 = st;        float* st_v1 = st + 256;
  float* st_v2 = st + 512;  float* st_e2 = st + 768;
  float* ss_v1 = ssb;       float* ss_e1 = ssb + 256;
  float* ss_v2 = ssb + 512; float* ss_e2 = ssb + 768;

  // zero the accumulated buffers: wV + z + stats (contiguous)
  (void)hipMemsetAsync(ws + WV_OFF, 0, 25600000 + 1600000 + 4096, stream);

  WPrep wp;
  const int wid[10] = {5,6,7,8,9,11,21,23,25,27};
  const int Ks[10]  = {128,128,128,128,128,128,128,256,128,256};
  const int Ns[10]  = {128,128,128,128,128,128,256,128,256,128};
  int cum = 0, off = 0;
  for (int i = 0; i < 10; i++){
    wp.w[i] = (const float*)d_in[wid[i]];
    wp.Kd[i] = Ks[i]; wp.Nd[i] = Ns[i];
    wp.off[i] = off; wp.cum[i] = cum;
    off += Ks[i]*Ns[i]*2; cum += Ks[i]*Ns[i];
  }
  k_wprep<<<896, 256, 0, stream>>>(wp, img, cum);

  k_qkv<<<391, 512, 0, stream>>>(v, img, Qp, Kp, Vp, N_NODES);

  k_edge<<<3907, 512, 0, stream>>>(e, envl, src, dst, Qp, Kp, Vp,
                                   img + 98304 /*We*/, img + 163840 /*WO_e*/, bOe,
                                   out_e, wVp, zp, st_e1, N_EDGES);

  k_nodeout<<<391, 512, 0, stream>>>(wVp, zp, v, img + 131072 /*WO_v*/, bOv,
                                     out_v, st_v1, N_NODES);

  {
    FinArgs fv{st_v1, g1v, b1vn, ss_v1, 1.f / N_NODES};
    FinArgs fe{st_e1, g1e, b1en, ss_e1, 1.f / N_EDGES};
    k_finstats<<<2, 128, 0, stream>>>(fv, fe);
  }

  k_ffn<<<391, 512, 0, stream>>>(out_v, ss_v1, img + 196608 /*W1v*/, b1vf,
                                 img + 262144 /*W2v*/, b2vf, st_v2, N_NODES);
  k_ffn<<<3907, 512, 0, stream>>>(out_e, ss_e1, img + 327680 /*W1e*/, b1ef,
                                  img + 393216 /*W2e*/, b2ef, st_e2, N_EDGES);

  {
    FinArgs fv{st_v2, g2v, b2vn, ss_v2, 1.f / N_NODES};
    FinArgs fe{st_e2, g2e, b2en, ss_e2, 1.f / N_EDGES};
    k_finstats<<<2, 128, 0, stream>>>(fv, fe);
  }

  k_norm<<<2048, 256, 0, stream>>>(out_v, ss_v2, (long long)(N_NODES) * DIM / 4);
  k_norm<<<4096, 256, 0, stream>>>(out_e, ss_e2, (long long)(N_EDGES) * DIM / 4);
}

// Round 2
// 1069.606 us; speedup vs baseline: 3.9377x; 3.9377x over previous
//
#include <hip/hip_runtime.h>
#include <hip/hip_bf16.h>

#define N_NODES 50000
#define N_EDGES 500000
#define DIM 128

typedef __bf16 bf16_t;
typedef __bf16 bf16x8 __attribute__((ext_vector_type(8)));
typedef float f32x4 __attribute__((ext_vector_type(4)));

#define MFMA(a,b,c) __builtin_amdgcn_mfma_f32_16x16x32_bf16((a),(b),(c),0,0,0)

// XOR swizzle (guide G4): kills 32-way bank conflicts for 256B/512B-stride rows
__device__ __forceinline__ int swz(int row, int kbyte){ return kbyte ^ ((row & 7) << 4); }

__device__ __forceinline__ bf16x8 lds_frag(const char* s, int row, int rowb, int kbyte){
  return *(const bf16x8*)(s + row * rowb + swz(row, kbyte));
}

__device__ __forceinline__ void copy16(char* dst, const char* __restrict__ src, int bytes){
  for (int o = threadIdx.x * 16; o < bytes; o += blockDim.x * 16)
    *(f32x4*)(dst + o) = *(const f32x4*)(src + o);
}

// copy a 256B-per-row half out of a 512B-per-row image (swizzle only touches bits 4..6, stays in-half)
__device__ __forceinline__ void copy_half(char* dst, const char* __restrict__ src, int halfOff){
  for (int o = threadIdx.x * 16; o < 32768; o += blockDim.x * 16){
    int row = o >> 8, off = o & 255;
    *(f32x4*)(dst + o) = *(const f32x4*)(src + row * 512 + halfOff + off);
  }
}

// ---------------- weight prep: f32 [K][N] -> bf16 transposed swizzled image [n][k] ----------------
struct WPrep {
  const float* w[10];
  int Kd[10], Nd[10], off[10], cum[10];
};

__global__ void k_wprep(WPrep d, char* img, int total){
  for (int idx = blockIdx.x * blockDim.x + threadIdx.x; idx < total; idx += gridDim.x * blockDim.x){
    int i = 0;
#pragma unroll
    for (int j = 1; j < 10; j++) if (idx >= d.cum[j]) i = j;
    int loc = idx - d.cum[i];
    int K = d.Kd[i], N = d.Nd[i];
    int n = loc / K, k = loc - n * K;
    float val = d.w[i][(size_t)k * N + n];
    *(bf16_t*)(img + d.off[i] + n * (K * 2) + swz(n, k * 2)) = (bf16_t)val;
  }
}

// ---------------- CSR build ----------------
__global__ void k_count(const int* __restrict__ dst, int* __restrict__ cnt){
  int i = blockIdx.x * blockDim.x + threadIdx.x;
  if (i < N_EDGES) atomicAdd(&cnt[dst[i]], 1);
}

__global__ __launch_bounds__(1024) void k_scan(const int* __restrict__ cnt,
                                               int* __restrict__ rowptr, int* __restrict__ wp){
  __shared__ int wsum[16];
  __shared__ int wpre[16];
  __shared__ int scarry;
  const int tid = threadIdx.x, lane = tid & 63, wv = tid >> 6;
  if (tid == 0) scarry = 0;
  for (int base = 0; base < N_NODES; base += 1024){
    int i = base + tid;
    int v = (i < N_NODES) ? cnt[i] : 0;
    int x = v;
#pragma unroll
    for (int off = 1; off < 64; off <<= 1){
      int t = __shfl_up(x, off);
      if (lane >= off) x += t;
    }
    if (lane == 63) wsum[wv] = x;
    __syncthreads();
    if (tid == 0){
      int run = scarry;
#pragma unroll
      for (int j = 0; j < 16; j++){ int t = wsum[j]; wpre[j] = run; run += t; }
      scarry = run;
    }
    __syncthreads();
    int excl = wpre[wv] + x - v;
    if (i < N_NODES){ rowptr[i] = excl; wp[i] = excl; }
    __syncthreads();
  }
  if (tid == 0) rowptr[N_NODES] = scarry;
}

__global__ void k_fill(const int* __restrict__ dst, int* __restrict__ wp, int* __restrict__ csr){
  int i = blockIdx.x * blockDim.x + threadIdx.x;
  if (i < N_EDGES){
    int p = atomicAdd(&wp[dst[i]], 1);
    csr[p] = i;
  }
}

// ---------------- QKV: [M,128] @ 3x [128,128] (one 32KB weight buffer, looped) ----------------
__global__ __launch_bounds__(512) void k_qkv(
    const float* __restrict__ v, const char* __restrict__ img,
    float* __restrict__ Q, float* __restrict__ K, float* __restrict__ V, int M)
{
  __shared__ __align__(16) char sm[65536];
  char* sX = sm;
  char* sW = sm + 32768;
  const int tid = threadIdx.x, lane = tid & 63, wave = tid >> 6;
  const int r0 = blockIdx.x * 128;
  for (int c = tid; c < 2048; c += 512){
    int row = c >> 4, kc = c & 15, grow = r0 + row;
    float f[8];
    if (grow < M){
      const float4* p = (const float4*)(v + (size_t)grow * DIM + kc * 8);
      float4 u0 = p[0], u1 = p[1];
      f[0]=u0.x; f[1]=u0.y; f[2]=u0.z; f[3]=u0.w;
      f[4]=u1.x; f[5]=u1.y; f[6]=u1.z; f[7]=u1.w;
    } else {
#pragma unroll
      for (int j=0;j<8;j++) f[j] = 0.f;
    }
    bf16x8 o;
#pragma unroll
    for (int j=0;j<8;j++) o[j] = (bf16_t)f[j];
    *(bf16x8*)(sX + row * 256 + swz(row, kc * 16)) = o;
  }
  const int rowA = wave * 16 + (lane & 15);
  const int kb0 = (lane >> 4) * 16;
  const int crow = wave*16 + (lane >> 4)*4;
  const int ccol = lane & 15;
  const f32x4 zero4 = {0.f, 0.f, 0.f, 0.f};
#pragma unroll
  for (int w3 = 0; w3 < 3; w3++){
    __syncthreads();            // staging done / prev GEMM done with sW
    copy16(sW, img + w3 * 32768, 32768);
    __syncthreads();
    f32x4 acc[8];
#pragma unroll
    for (int b=0;b<8;b++) acc[b] = zero4;
#pragma unroll
    for (int ks=0; ks<4; ks++){
      bf16x8 a = lds_frag(sX, rowA, 256, ks*64 + kb0);
#pragma unroll
      for (int nt=0; nt<8; nt++){
        int rn = nt*16 + (lane & 15);
        bf16x8 b = lds_frag(sW, rn, 256, ks*64 + kb0);
        acc[nt] = MFMA(a, b, acc[nt]);
      }
    }
    float* o = (w3 == 0) ? Q : ((w3 == 1) ? K : V);
#pragma unroll
    for (int nt=0; nt<8; nt++)
#pragma unroll
      for (int r=0; r<4; r++){
        int grow = r0 + crow + r;
        if (grow < M) o[(size_t)grow * DIM + nt*16 + ccol] = acc[nt][r];
      }
  }
}

// ---------------- fused edge attention (no scatter; s written per edge) ----------------
__global__ __launch_bounds__(512) void k_edge(
    const float* __restrict__ e,
    const int* __restrict__ src, const int* __restrict__ dst,
    const float* __restrict__ Q, const float* __restrict__ K,
    const char* __restrict__ imgWe, const char* __restrict__ imgWo,
    const float* __restrict__ bOe,
    float* __restrict__ e1_pre, float* __restrict__ sv,
    float* __restrict__ stats, int M)
{
  __shared__ __align__(16) char sm[68096];
  char* sW = sm;                          // 32KB: We then WO_e
  char* sX = sm + 32768;                  // 32KB: e tile, then score
  float* sStats = (float*)(sm + 65536);   // 256 f
  int* sSrc = (int*)(sm + 66560);
  int* sDst = (int*)(sm + 67072);
  const int tid = threadIdx.x, lane = tid & 63, wave = tid >> 6;
  const int r0 = blockIdx.x * 128;
  copy16(sW, imgWe, 32768);
  if (tid < 128){
    int ed = r0 + tid;
    sSrc[tid] = (ed < M) ? src[ed] : 0;
    sDst[tid] = (ed < M) ? dst[ed] : 0;
  }
  if (tid < 256) sStats[tid] = 0.f;
  for (int c = tid; c < 2048; c += 512){
    int row = c >> 4, kc = c & 15, grow = r0 + row;
    float f[8];
    if (grow < M){
      const float4* p = (const float4*)(e + (size_t)grow * DIM + kc * 8);
      float4 u0 = p[0], u1 = p[1];
      f[0]=u0.x; f[1]=u0.y; f[2]=u0.z; f[3]=u0.w;
      f[4]=u1.x; f[5]=u1.y; f[6]=u1.z; f[7]=u1.w;
    } else {
#pragma unroll
      for (int j=0;j<8;j++) f[j] = 0.f;
    }
    bf16x8 o;
#pragma unroll
    for (int j=0;j<8;j++) o[j] = (bf16_t)f[j];
    *(bf16x8*)(sX + row * 256 + swz(row, kc * 16)) = o;
  }
  __syncthreads();
  const int rowA = wave * 16 + (lane & 15);
  const int kb0 = (lane >> 4) * 16;
  const f32x4 zero4 = {0.f,0.f,0.f,0.f};
  f32x4 pe[8];
#pragma unroll
  for (int i=0;i<8;i++) pe[i] = zero4;
#pragma unroll
  for (int ks=0; ks<4; ks++){
    bf16x8 a = lds_frag(sX, rowA, 256, ks*64 + kb0);
#pragma unroll
    for (int nt=0; nt<8; nt++){
      int rn = nt*16 + (lane & 15);
      bf16x8 b = lds_frag(sW, rn, 256, ks*64 + kb0);
      pe[nt] = MFMA(a, b, pe[nt]);
    }
  }
  __syncthreads();   // done reading sX (e tile) and sW (We)
  copy16(sW, imgWo, 32768);               // WO_e into the same buffer
  const int crow = wave*16 + (lane >> 4)*4;
  const int ccol = lane & 15;
  const float* Kb[4]; const float* Qb[4];
#pragma unroll
  for (int r=0;r<4;r++){
    int row = crow + r;
    Kb[r] = K + (size_t)sSrc[row] * DIM;
    Qb[r] = Q + (size_t)sDst[row] * DIM;
  }
#pragma unroll
  for (int nt=0; nt<8; nt++){
    float sc[4];
#pragma unroll
    for (int r=0;r<4;r++){
      int col = nt*16 + ccol;
      sc[r] = pe[nt][r] * 0.25f * Kb[r][col] * Qb[r][col];
    }
#pragma unroll
    for (int r=0;r<4;r++){
      int row = crow + r, col = nt*16 + ccol;
      *(bf16_t*)(sX + row*256 + swz(row, col*2)) = (bf16_t)sc[r];
      float hv = sc[r];
      hv += __shfl_xor(hv, 1);
      hv += __shfl_xor(hv, 2);
      hv += __shfl_xor(hv, 4);
      hv += __shfl_xor(hv, 8);
      if (ccol == 0){
        int ed = r0 + row;
        if (ed < M)
          sv[(size_t)ed*8 + nt] = expf(fminf(5.f, fmaxf(-5.f, hv)));
      }
    }
  }
  __syncthreads();
  // GEMM2: e_attn @ WO_e
  f32x4 a2[8];
#pragma unroll
  for (int i=0;i<8;i++) a2[i] = zero4;
#pragma unroll
  for (int ks=0; ks<4; ks++){
    bf16x8 a = lds_frag(sX, rowA, 256, ks*64 + kb0);
#pragma unroll
    for (int nt=0; nt<8; nt++){
      int rn = nt*16 + (lane & 15);
      bf16x8 b = lds_frag(sW, rn, 256, ks*64 + kb0);
      a2[nt] = MFMA(a, b, a2[nt]);
    }
  }
  // epilogue: e1_pre = e + attn_out + bOe ; BN stats
#pragma unroll
  for (int nt=0; nt<8; nt++){
    float s1 = 0.f, s2 = 0.f;
#pragma unroll
    for (int r=0; r<4; r++){
      int row = crow + r, col = nt*16 + ccol;
      int ed = r0 + row;
      float val = 0.f;
      if (ed < M){
        val = a2[nt][r] + e[(size_t)ed * DIM + col] + bOe[col];
        e1_pre[(size_t)ed * DIM + col] = val;
      }
      s1 += val; s2 += val * val;
    }
    s1 += __shfl_xor(s1, 16); s1 += __shfl_xor(s1, 32);
    s2 += __shfl_xor(s2, 16); s2 += __shfl_xor(s2, 32);
    if (lane < 16){
      atomicAdd(&sStats[nt*16 + ccol], s1);
      atomicAdd(&sStats[128 + nt*16 + ccol], s2);
    }
  }
  __syncthreads();
  if (tid < 256) unsafeAtomicAdd(&stats[tid], sStats[tid]);
}

// ---------------- aggregation: one wave per node, CSR walk, no atomics ----------------
__global__ __launch_bounds__(512) void k_agg(
    const int* __restrict__ rowptr, const int* __restrict__ csr,
    const int* __restrict__ src, const float* __restrict__ envl,
    const float* __restrict__ sv, const float* __restrict__ V,
    float* __restrict__ vAttn, int M)
{
  const int wave = threadIdx.x >> 6, lane = threadIdx.x & 63;
  const int n = blockIdx.x * 8 + wave;
  if (n >= M) return;
  const int beg = rowptr[n], end = rowptr[n + 1];
  const int h = lane >> 3;           // head of cols (2*lane, 2*lane+1)
  float ax = 0.f, ay = 0.f, zacc = 0.f;
  for (int i = beg; i < end; i++){
    int eid = csr[i];
    int sn = src[eid];
    float s = sv[(size_t)eid * 8 + h];
    float env = envl[eid];
    const float2 vv = *(const float2*)(V + (size_t)sn * DIM + lane * 2);
    float w = env * s;
    ax += vv.x * w; ay += vv.y * w;
    zacc += s;
  }
  float inv = 1.f / (zacc + 1e-6f);
  float2 o; o.x = ax * inv; o.y = ay * inv;
  *(float2*)(vAttn + (size_t)n * DIM + lane * 2) = o;
}

// ---------------- node: v1_pre = v + v_attn@WO_v + bOv; stats ----------------
__global__ __launch_bounds__(512) void k_nodeout(
    const float* __restrict__ vAttn, const float* __restrict__ v,
    const char* __restrict__ imgWo, const float* __restrict__ bOv,
    float* __restrict__ v1_pre, float* __restrict__ stats, int M)
{
  __shared__ __align__(16) char sm[66560];
  char* sW = sm;
  char* sX = sm + 32768;
  float* sStats = (float*)(sm + 65536);
  const int tid = threadIdx.x, lane = tid & 63, wave = tid >> 6;
  const int r0 = blockIdx.x * 128;
  copy16(sW, imgWo, 32768);
  if (tid < 256) sStats[tid] = 0.f;
  for (int c = tid; c < 2048; c += 512){
    int row = c >> 4, kc = c & 15, grow = r0 + row;
    float f[8];
    if (grow < M){
      const float4* p = (const float4*)(vAttn + (size_t)grow * DIM + kc * 8);
      float4 u0 = p[0], u1 = p[1];
      f[0]=u0.x; f[1]=u0.y; f[2]=u0.z; f[3]=u0.w;
      f[4]=u1.x; f[5]=u1.y; f[6]=u1.z; f[7]=u1.w;
    } else {
#pragma unroll
      for (int j=0;j<8;j++) f[j]=0.f;
    }
    bf16x8 o;
#pragma unroll
    for (int j=0;j<8;j++) o[j]=(bf16_t)f[j];
    *(bf16x8*)(sX + row*256 + swz(row, kc*16)) = o;
  }
  __syncthreads();
  const int rowA = wave*16 + (lane & 15);
  const int kb0 = (lane >> 4)*16;
  const f32x4 zero4 = {0.f,0.f,0.f,0.f};
  f32x4 acc[8];
#pragma unroll
  for (int i=0;i<8;i++) acc[i]=zero4;
#pragma unroll
  for (int ks=0;ks<4;ks++){
    bf16x8 a = lds_frag(sX, rowA, 256, ks*64+kb0);
#pragma unroll
    for (int nt=0;nt<8;nt++){
      int rn = nt*16 + (lane&15);
      bf16x8 b = lds_frag(sW, rn, 256, ks*64+kb0);
      acc[nt] = MFMA(a,b,acc[nt]);
    }
  }
  const int crow = wave*16 + (lane>>4)*4;
  const int ccol = lane & 15;
#pragma unroll
  for (int nt=0;nt<8;nt++){
    float s1=0.f, s2=0.f;
#pragma unroll
    for (int r=0;r<4;r++){
      int grow = r0 + crow + r, col = nt*16 + ccol;
      float val = 0.f;
      if (grow < M){
        val = acc[nt][r] + v[(size_t)grow*DIM + col] + bOv[col];
        v1_pre[(size_t)grow*DIM + col] = val;
      }
      s1 += val; s2 += val*val;
    }
    s1 += __shfl_xor(s1,16); s1 += __shfl_xor(s1,32);
    s2 += __shfl_xor(s2,16); s2 += __shfl_xor(s2,32);
    if (lane < 16){
      atomicAdd(&sStats[nt*16+ccol], s1);
      atomicAdd(&sStats[128+nt*16+ccol], s2);
    }
  }
  __syncthreads();
  if (tid < 256) unsafeAtomicAdd(&stats[tid], sStats[tid]);
}

// ---------------- fused FFN (weights in 32KB halves for 2-block occupancy) ----------------
__global__ __launch_bounds__(512) void k_ffn(
    float* __restrict__ xio, const float* __restrict__ ss1,
    const char* __restrict__ img1, const float* __restrict__ b1,
    const char* __restrict__ img2, const float* __restrict__ b2,
    float* __restrict__ stats2, int M)
{
  __shared__ __align__(16) char sm[66560];
  char* sX = sm;           // x1 tile (bf16), then relu(h half) tile
  char* sW = sm + 32768;   // W1h0, W1h1, W2h0, W2h1
  float* sStats = (float*)(sm + 65536);
  const int tid = threadIdx.x, lane = tid & 63, wave = tid >> 6;
  const int r0 = blockIdx.x * 128;
  copy16(sW, img1, 32768);
  if (tid < 256) sStats[tid] = 0.f;
  for (int c = tid; c < 2048; c += 512){
    int row = c >> 4, kc = c & 15, grow = r0 + row;
    float f[8];
    if (grow < M){
      const float4* p = (const float4*)(xio + (size_t)grow*DIM + kc*8);
      float4 u0 = p[0], u1 = p[1];
      f[0]=u0.x; f[1]=u0.y; f[2]=u0.z; f[3]=u0.w;
      f[4]=u1.x; f[5]=u1.y; f[6]=u1.z; f[7]=u1.w;
#pragma unroll
      for (int j=0;j<8;j++){ int col = kc*8 + j; f[j] = f[j]*ss1[col] + ss1[128+col]; }
    } else {
#pragma unroll
      for (int j=0;j<8;j++) f[j]=0.f;
    }
    bf16x8 o;
#pragma unroll
    for (int j=0;j<8;j++) o[j]=(bf16_t)f[j];
    *(bf16x8*)(sX + row*256 + swz(row, kc*16)) = o;
  }
  __syncthreads();
  const int rowA = wave*16 + (lane & 15);
  const int kb0 = (lane >> 4) * 16;
  const f32x4 zero4 = {0.f,0.f,0.f,0.f};
  f32x4 h[16];
#pragma unroll
  for (int i=0;i<16;i++) h[i]=zero4;
  // GEMM1 half0 (hidden cols 0..127)
#pragma unroll
  for (int ks=0;ks<4;ks++){
    bf16x8 a = lds_frag(sX, rowA, 256, ks*64+kb0);
#pragma unroll
    for (int nt=0;nt<8;nt++){
      int rn = nt*16 + (lane&15);
      bf16x8 b = lds_frag(sW, rn, 256, ks*64+kb0);
      h[nt] = MFMA(a,b,h[nt]);
    }
  }
  __syncthreads();
  copy16(sW, img1 + 32768, 32768);   // W1 half1
  __syncthreads();
#pragma unroll
  for (int ks=0;ks<4;ks++){
    bf16x8 a = lds_frag(sX, rowA, 256, ks*64+kb0);
#pragma unroll
    for (int nt=0;nt<8;nt++){
      int rn = nt*16 + (lane&15);
      bf16x8 b = lds_frag(sW, rn, 256, ks*64+kb0);
      h[8+nt] = MFMA(a,b,h[8+nt]);
    }
  }
  __syncthreads();    // done with sX (x tile) and sW
  const int crow = wave*16 + (lane>>4)*4;
  const int ccol = lane & 15;
  f32x4 o2[8];
#pragma unroll
  for (int i=0;i<8;i++) o2[i]=zero4;
#pragma unroll
  for (int half = 0; half < 2; half++){
    // write relu(h half) into sX
#pragma unroll
    for (int nt=0;nt<8;nt++)
#pragma unroll
      for (int r=0;r<4;r++){
        int row = crow + r, col = nt*16 + ccol;
        float hv = fmaxf(h[half*8+nt][r] + b1[half*128 + col], 0.f);
        *(bf16_t*)(sX + row*256 + swz(row, col*2)) = (bf16_t)hv;
      }
    copy_half(sW, img2, half * 256);   // W2 rows, k-half
    __syncthreads();
#pragma unroll
    for (int ks=0;ks<4;ks++){
      bf16x8 a = lds_frag(sX, rowA, 256, ks*64+kb0);
#pragma unroll
      for (int nt=0;nt<8;nt++){
        int rn = nt*16 + (lane&15);
        bf16x8 b = lds_frag(sW, rn, 256, ks*64+kb0);
        o2[nt] = MFMA(a,b,o2[nt]);
      }
    }
    __syncthreads();
  }
#pragma unroll
  for (int nt=0;nt<8;nt++){
    float s1=0.f, s2=0.f;
#pragma unroll
    for (int r=0;r<4;r++){
      int row = crow + r, col = nt*16 + ccol;
      int grow = r0 + row;
      float val = 0.f;
      if (grow < M){
        float xp = xio[(size_t)grow*DIM + col];
        float x1 = xp*ss1[col] + ss1[128+col];
        val = x1 + o2[nt][r] + b2[col];
        xio[(size_t)grow*DIM + col] = val;
      }
      s1 += val; s2 += val*val;
    }
    s1 += __shfl_xor(s1,16); s1 += __shfl_xor(s1,32);
    s2 += __shfl_xor(s2,16); s2 += __shfl_xor(s2,32);
    if (lane < 16){
      atomicAdd(&sStats[nt*16+ccol], s1);
      atomicAdd(&sStats[128+nt*16+ccol], s2);
    }
  }
  __syncthreads();
  if (tid < 256) unsafeAtomicAdd(&stats2[tid], sStats[tid]);
}

// ---------------- stats -> scale/shift ----------------
struct FinArgs { const float* st; const float* g; const float* b; float* ss; float invM; };

__global__ void k_finstats(FinArgs a0, FinArgs a1){
  FinArgs a = (blockIdx.x == 0) ? a0 : a1;
  int c = threadIdx.x;
  float mean = a.st[c] * a.invM;
  float var  = a.st[128 + c] * a.invM - mean * mean;
  float scl  = a.g[c] * rsqrtf(var + 1e-5f);
  a.ss[c] = scl;
  a.ss[128 + c] = a.b[c] - mean * scl;
}

// ---------------- in-place normalize ----------------
__global__ void k_norm(float* __restrict__ x, const float* __restrict__ ss, long long n4){
  for (long long i = (long long)blockIdx.x * blockDim.x + threadIdx.x; i < n4;
       i += (long long)gridDim.x * blockDim.x){
    float4* p = (float4*)x + i;
    float4 t = *p;
    int c0 = (int)((i * 4) & 127);
    t.x = t.x * ss[c0]     + ss[128 + c0];
    t.y = t.y * ss[c0 + 1] + ss[128 + c0 + 1];
    t.z = t.z * ss[c0 + 2] + ss[128 + c0 + 2];
    t.w = t.w * ss[c0 + 3] + ss[128 + c0 + 3];
    *p = t;
  }
}

extern "C" void kernel_launch(void* const* d_in, const int* in_sizes, int n_in,
                              void* d_out, int out_size, void* d_ws, size_t ws_size,
                              hipStream_t stream)
{
  const float* v    = (const float*)d_in[0];
  const float* e    = (const float*)d_in[1];
  const float* envl = (const float*)d_in[2];
  const int*   src  = (const int*)d_in[3];
  const int*   dst  = (const int*)d_in[4];
  const float* bOv  = (const float*)d_in[10];
  const float* bOe  = (const float*)d_in[12];
  const float* g1v  = (const float*)d_in[13];
  const float* b1vn = (const float*)d_in[14];
  const float* g1e  = (const float*)d_in[15];
  const float* b1en = (const float*)d_in[16];
  const float* g2v  = (const float*)d_in[17];
  const float* b2vn = (const float*)d_in[18];
  const float* g2e  = (const float*)d_in[19];
  const float* b2en = (const float*)d_in[20];
  const float* b1vf = (const float*)d_in[22];
  const float* b2vf = (const float*)d_in[24];
  const float* b1ef = (const float*)d_in[26];
  const float* b2ef = (const float*)d_in[28];

  float* out_v = (float*)d_out;
  float* out_e = out_v + (size_t)N_NODES * DIM;

  char* ws = (char*)d_ws;
  const size_t IMG_OFF = 0;                        // 458752 B of bf16 weight images
  const size_t Q_OFF   = 458752;                   // Q; reused as vAttn by k_agg
  const size_t K_OFF   = Q_OFF  + 25600000;
  const size_t V_OFF   = K_OFF  + 25600000;
  const size_t SV_OFF  = V_OFF  + 25600000;        // s per edge per head: E*8*4 = 16MB
  const size_t CSR_OFF = SV_OFF + 16000000;        // E ints
  const size_t RP_OFF  = CSR_OFF + 2000000;        // N+1 ints
  const size_t WP_OFF  = RP_OFF  + 200016;         // N ints
  const size_t CNT_OFF = WP_OFF  + 200000;         // N ints (memset 0)
  const size_t ST_OFF  = CNT_OFF + 200000;         // 1024 f (memset 0)
  const size_t SS_OFF  = ST_OFF  + 4096;           // 1024 f

  char*  img   = ws + IMG_OFF;
  float* Qp    = (float*)(ws + Q_OFF);
  float* Kp    = (float*)(ws + K_OFF);
  float* Vp    = (float*)(ws + V_OFF);
  float* svp   = (float*)(ws + SV_OFF);
  int*   csr   = (int*)(ws + CSR_OFF);
  int*   rowp  = (int*)(ws + RP_OFF);
  int*   wpp   = (int*)(ws + WP_OFF);
  int*   cnt   = (int*)(ws + CNT_OFF);
  float* st    = (float*)(ws + ST_OFF);
  float* ssb   = (float*)(ws + SS_OFF);
  float* vAttn = Qp;   // Q is dead after k_edge
  float* st_e1 = st;        float* st_v1 = st + 256;
  float* st_v2 = st + 512;  float* st_e2 = st + 768;
  float* ss_v1 = ssb;       float* ss_e1 = ssb + 256;
  float* ss_v2 = ssb + 512; float* ss_e2 = ssb + 768;

  // zero counters + stats (contiguous)
  (void)hipMemsetAsync(ws + CNT_OFF, 0, 200000 + 4096, stream);

  WPrep wp;
  const int wid[10] = {5,6,7,8,9,11,21,23,25,27};
  const int Ks[10]  = {128,128,128,128,128,128,128,256,128,256};
  const int Ns[10]  = {128,128,128,128,128,128,256,128,256,128};
  int cum = 0, off = 0;
  for (int i = 0; i < 10; i++){
    wp.w[i] = (const float*)d_in[wid[i]];
    wp.Kd[i] = Ks[i]; wp.Nd[i] = Ns[i];
    wp.off[i] = off; wp.cum[i] = cum;
    off += Ks[i]*Ns[i]*2; cum += Ks[i]*Ns[i];
  }
  k_wprep<<<896, 256, 0, stream>>>(wp, img, cum);

  // CSR build (independent of QKV)
  k_count<<<1954, 256, 0, stream>>>(dst, cnt);
  k_scan<<<1, 1024, 0, stream>>>(cnt, rowp, wpp);
  k_fill<<<1954, 256, 0, stream>>>(dst, wpp, csr);

  k_qkv<<<391, 512, 0, stream>>>(v, img, Qp, Kp, Vp, N_NODES);

  k_edge<<<3907, 512, 0, stream>>>(e, src, dst, Qp, Kp,
                                   img + 98304 /*We*/, img + 163840 /*WO_e*/, bOe,
                                   out_e, svp, st_e1, N_EDGES);

  k_agg<<<6250, 512, 0, stream>>>(rowp, csr, src, envl, svp, Vp, vAttn, N_NODES);

  k_nodeout<<<391, 512, 0, stream>>>(vAttn, v, img + 131072 /*WO_v*/, bOv,
                                     out_v, st_v1, N_NODES);

  {
    FinArgs fv{st_v1, g1v, b1vn, ss_v1, 1.f / N_NODES};
    FinArgs fe{st_e1, g1e, b1en, ss_e1, 1.f / N_EDGES};
    k_finstats<<<2, 128, 0, stream>>>(fv, fe);
  }

  k_ffn<<<391, 512, 0, stream>>>(out_v, ss_v1, img + 196608 /*W1v*/, b1vf,
                                 img + 262144 /*W2v*/, b2vf, st_v2, N_NODES);
  k_ffn<<<3907, 512, 0, stream>>>(out_e, ss_e1, img + 327680 /*W1e*/, b1ef,
                                  img + 393216 /*W2e*/, b2ef, st_e2, N_EDGES);

  {
    FinArgs fv{st_v2, g2v, b2vn, ss_v2, 1.f / N_NODES};
    FinArgs fe{st_e2, g2e, b2en, ss_e2, 1.f / N_EDGES};
    k_finstats<<<2, 128, 0, stream>>>(fv, fe);
  }

  k_norm<<<2048, 256, 0, stream>>>(out_v, ss_v2, (long long)(N_NODES) * DIM / 4);
  k_norm<<<4096, 256, 0, stream>>>(out_e, ss_e2, (long long)(N_EDGES) * DIM / 4);
}

// Round 3
// 961.371 us; speedup vs baseline: 4.3810x; 1.1126x over previous
//
#include <hip/hip_runtime.h>
#include <hip/hip_bf16.h>

#define N_NODES 50000
#define N_EDGES 500000
#define DIM 128

typedef __bf16 bf16_t;
typedef __bf16 bf16x8 __attribute__((ext_vector_type(8)));
typedef __bf16 bf16x2 __attribute__((ext_vector_type(2)));
typedef float f32x4 __attribute__((ext_vector_type(4)));

#define MFMA(a,b,c) __builtin_amdgcn_mfma_f32_16x16x32_bf16((a),(b),(c),0,0,0)

// XOR swizzle (guide G4): kills 32-way bank conflicts for 256B/512B-stride rows
__device__ __forceinline__ int swz(int row, int kbyte){ return kbyte ^ ((row & 7) << 4); }

__device__ __forceinline__ bf16x8 lds_frag(const char* s, int row, int rowb, int kbyte){
  return *(const bf16x8*)(s + row * rowb + swz(row, kbyte));
}

__device__ __forceinline__ void copy16(char* dst, const char* __restrict__ src, int bytes){
  for (int o = threadIdx.x * 16; o < bytes; o += blockDim.x * 16)
    *(f32x4*)(dst + o) = *(const f32x4*)(src + o);
}

// copy a 256B-per-row half out of a 512B-per-row image (swizzle only touches bits 4..6, stays in-half)
__device__ __forceinline__ void copy_half(char* dst, const char* __restrict__ src, int halfOff){
  for (int o = threadIdx.x * 16; o < 32768; o += blockDim.x * 16){
    int row = o >> 8, off = o & 255;
    *(f32x4*)(dst + o) = *(const f32x4*)(src + row * 512 + halfOff + off);
  }
}

// ---------------- weight prep: f32 [K][N] -> bf16 transposed swizzled image [n][k] ----------------
// mode 1: permute output-col index n -> (n&7)*16 + (n>>3)   (We: contiguous logical cols per MFMA thread)
// mode 2: permute K-row index k the same way                 (WO_e: must match score's physical K order)
struct WPrep {
  const float* w[10];
  int Kd[10], Nd[10], off[10], cum[10], mode[10];
};

__global__ void k_wprep(WPrep d, char* img, int total){
  for (int idx = blockIdx.x * blockDim.x + threadIdx.x; idx < total; idx += gridDim.x * blockDim.x){
    int i = 0;
#pragma unroll
    for (int j = 1; j < 10; j++) if (idx >= d.cum[j]) i = j;
    int loc = idx - d.cum[i];
    int K = d.Kd[i], N = d.Nd[i];
    int n = loc / K, k = loc - n * K;
    float val = d.w[i][(size_t)k * N + n];
    int nn = n, kk = k;
    if (d.mode[i] == 1) nn = ((n & 7) << 4) | (n >> 3);
    if (d.mode[i] == 2) kk = ((k & 7) << 4) | (k >> 3);
    *(bf16_t*)(img + d.off[i] + nn * (K * 2) + swz(nn, kk * 2)) = (bf16_t)val;
  }
}

// ---------------- CSR build ----------------
__global__ void k_count(const int* __restrict__ dst, int* __restrict__ cnt){
  int i = blockIdx.x * blockDim.x + threadIdx.x;
  if (i < N_EDGES) atomicAdd(&cnt[dst[i]], 1);
}

__global__ __launch_bounds__(1024) void k_scan(const int* __restrict__ cnt,
                                               int* __restrict__ rowptr, int* __restrict__ wp){
  __shared__ int wsum[16];
  __shared__ int wpre[16];
  __shared__ int scarry;
  const int tid = threadIdx.x, lane = tid & 63, wv = tid >> 6;
  if (tid == 0) scarry = 0;
  for (int base = 0; base < N_NODES; base += 8192){
    int i0 = base + tid * 8;
    int v[8], p[8];
    int tsum = 0;
#pragma unroll
    for (int j = 0; j < 8; j++){
      int idx = i0 + j;
      v[j] = (idx < N_NODES) ? cnt[idx] : 0;
      p[j] = tsum; tsum += v[j];
    }
    int x = tsum;
#pragma unroll
    for (int off = 1; off < 64; off <<= 1){
      int t = __shfl_up(x, off);
      if (lane >= off) x += t;
    }
    if (lane == 63) wsum[wv] = x;
    __syncthreads();
    if (tid == 0){
      int run = scarry;
#pragma unroll
      for (int j = 0; j < 16; j++){ int t = wsum[j]; wpre[j] = run; run += t; }
      scarry = run;
    }
    __syncthreads();
    int texcl = wpre[wv] + x - tsum;
#pragma unroll
    for (int j = 0; j < 8; j++){
      int idx = i0 + j;
      if (idx < N_NODES){ rowptr[idx] = texcl + p[j]; wp[idx] = texcl + p[j]; }
    }
  }
  __syncthreads();
  if (tid == 0) rowptr[N_NODES] = scarry;
}

__global__ void k_fill(const int* __restrict__ dst, int* __restrict__ wp, int* __restrict__ csr){
  int i = blockIdx.x * blockDim.x + threadIdx.x;
  if (i < N_EDGES){
    int p = atomicAdd(&wp[dst[i]], 1);
    csr[p] = i;
  }
}

// ---------------- QKV: [M,128] @ 3x [128,128] -> bf16 outputs ----------------
__global__ __launch_bounds__(512) void k_qkv(
    const float* __restrict__ v, const char* __restrict__ img,
    bf16_t* __restrict__ Q, bf16_t* __restrict__ K, bf16_t* __restrict__ V, int M)
{
  __shared__ __align__(16) char sm[65536];
  char* sX = sm;
  char* sW = sm + 32768;
  const int tid = threadIdx.x, lane = tid & 63, wave = tid >> 6;
  const int r0 = blockIdx.x * 128;
  for (int c = tid; c < 2048; c += 512){
    int row = c >> 4, kc = c & 15, grow = r0 + row;
    float f[8];
    if (grow < M){
      const float4* p = (const float4*)(v + (size_t)grow * DIM + kc * 8);
      float4 u0 = p[0], u1 = p[1];
      f[0]=u0.x; f[1]=u0.y; f[2]=u0.z; f[3]=u0.w;
      f[4]=u1.x; f[5]=u1.y; f[6]=u1.z; f[7]=u1.w;
    } else {
#pragma unroll
      for (int j=0;j<8;j++) f[j] = 0.f;
    }
    bf16x8 o;
#pragma unroll
    for (int j=0;j<8;j++) o[j] = (bf16_t)f[j];
    *(bf16x8*)(sX + row * 256 + swz(row, kc * 16)) = o;
  }
  const int rowA = wave * 16 + (lane & 15);
  const int kb0 = (lane >> 4) * 16;
  const int crow = wave*16 + (lane >> 4)*4;
  const int ccol = lane & 15;
  const f32x4 zero4 = {0.f, 0.f, 0.f, 0.f};
#pragma unroll
  for (int w3 = 0; w3 < 3; w3++){
    __syncthreads();            // staging done / prev GEMM done with sW
    copy16(sW, img + w3 * 32768, 32768);
    __syncthreads();
    f32x4 acc[8];
#pragma unroll
    for (int b=0;b<8;b++) acc[b] = zero4;
#pragma unroll
    for (int ks=0; ks<4; ks++){
      bf16x8 a = lds_frag(sX, rowA, 256, ks*64 + kb0);
#pragma unroll
      for (int nt=0; nt<8; nt++){
        int rn = nt*16 + (lane & 15);
        bf16x8 b = lds_frag(sW, rn, 256, ks*64 + kb0);
        acc[nt] = MFMA(a, b, acc[nt]);
      }
    }
    bf16_t* o = (w3 == 0) ? Q : ((w3 == 1) ? K : V);
#pragma unroll
    for (int nt=0; nt<8; nt++)
#pragma unroll
      for (int r=0; r<4; r++){
        int grow = r0 + crow + r;
        if (grow < M) o[(size_t)grow * DIM + nt*16 + ccol] = (bf16_t)acc[nt][r];
      }
  }
}

// ---------------- fused edge attention ----------------
// We image has permuted output cols (mode 1): C element (nt,ccol) = logical col ccol*8+nt.
// -> gathers are one bf16x8 per row per operand; head-sum = 8 in-thread adds + shfl_xor(1).
// Score written at physical K positions; WO_e image K-permuted (mode 2) to match.
__global__ __launch_bounds__(512, 4) void k_edge(
    const float* __restrict__ e,
    const int* __restrict__ src, const int* __restrict__ dst,
    const bf16_t* __restrict__ Qb, const bf16_t* __restrict__ Kb,
    const char* __restrict__ imgWe, const char* __restrict__ imgWo,
    const float* __restrict__ bOe,
    float* __restrict__ e1_pre, float* __restrict__ sv,
    float* __restrict__ stats, int M)
{
  __shared__ __align__(16) char sm[66560];
  char* sW = sm;                          // 32KB: We then WO_e
  char* sX = sm + 32768;                  // 32KB: e tile, then score
  float* sStats = (float*)(sm + 65536);   // 256 f
  const int tid = threadIdx.x, lane = tid & 63, wave = tid >> 6;
  const int r0 = blockIdx.x * 128;
  const int crow = wave*16 + (lane >> 4)*4;
  const int ccol = lane & 15;
  // prefetch K[src]/Q[dst] fragments (in flight through staging + GEMM1)
  bf16x8 Kg[4], Qg[4];
#pragma unroll
  for (int r=0;r<4;r++){
    int ed = r0 + crow + r; if (ed >= M) ed = M - 1;
    int sn = src[ed], dn = dst[ed];
    Kg[r] = *(const bf16x8*)(Kb + (size_t)sn * DIM + ccol * 8);
    Qg[r] = *(const bf16x8*)(Qb + (size_t)dn * DIM + ccol * 8);
  }
  copy16(sW, imgWe, 32768);
  if (tid < 256) sStats[tid] = 0.f;
  for (int c = tid; c < 2048; c += 512){
    int row = c >> 4, kc = c & 15, grow = r0 + row;
    float f[8];
    if (grow < M){
      const float4* p = (const float4*)(e + (size_t)grow * DIM + kc * 8);
      float4 u0 = p[0], u1 = p[1];
      f[0]=u0.x; f[1]=u0.y; f[2]=u0.z; f[3]=u0.w;
      f[4]=u1.x; f[5]=u1.y; f[6]=u1.z; f[7]=u1.w;
    } else {
#pragma unroll
      for (int j=0;j<8;j++) f[j] = 0.f;
    }
    bf16x8 o;
#pragma unroll
    for (int j=0;j<8;j++) o[j] = (bf16_t)f[j];
    *(bf16x8*)(sX + row * 256 + swz(row, kc * 16)) = o;
  }
  __syncthreads();
  const int rowA = wave * 16 + (lane & 15);
  const int kb0 = (lane >> 4) * 16;
  const f32x4 zero4 = {0.f,0.f,0.f,0.f};
  f32x4 pe[8];
#pragma unroll
  for (int i=0;i<8;i++) pe[i] = zero4;
#pragma unroll
  for (int ks=0; ks<4; ks++){
    bf16x8 a = lds_frag(sX, rowA, 256, ks*64 + kb0);
#pragma unroll
    for (int nt=0; nt<8; nt++){
      int rn = nt*16 + (lane & 15);
      bf16x8 b = lds_frag(sW, rn, 256, ks*64 + kb0);
      pe[nt] = MFMA(a, b, pe[nt]);
    }
  }
  __syncthreads();   // done reading sX (e tile) and sW (We)
  copy16(sW, imgWo, 32768);               // WO_e into the same buffer (overlaps score phase)
  // score in registers; pe[nt][r] * K/Q logical col ccol*8+nt
  float hs[4] = {0.f, 0.f, 0.f, 0.f};
#pragma unroll
  for (int nt=0; nt<8; nt++)
#pragma unroll
    for (int r=0;r<4;r++){
      float sc = pe[nt][r] * 0.25f * (float)Kg[r][nt] * (float)Qg[r][nt];
      int row = crow + r;
      *(bf16_t*)(sX + row*256 + swz(row, (nt*16 + ccol)*2)) = (bf16_t)sc;
      hs[r] += sc;
    }
#pragma unroll
  for (int r=0;r<4;r++){
    float t = hs[r] + __shfl_xor(hs[r], 1);   // pair covers the full 16-col head
    int ed = r0 + crow + r;
    if (!(ccol & 1) && ed < M)
      sv[(size_t)ed*8 + (ccol >> 1)] = __expf(fminf(5.f, fmaxf(-5.f, t)));
  }
  __syncthreads();
  // GEMM2: e_attn @ WO_e (K-permuted image matches score's physical order)
  f32x4 a2[8];
#pragma unroll
  for (int i=0;i<8;i++) a2[i] = zero4;
#pragma unroll
  for (int ks=0; ks<4; ks++){
    bf16x8 a = lds_frag(sX, rowA, 256, ks*64 + kb0);
#pragma unroll
    for (int nt=0; nt<8; nt++){
      int rn = nt*16 + (lane & 15);
      bf16x8 b = lds_frag(sW, rn, 256, ks*64 + kb0);
      a2[nt] = MFMA(a, b, a2[nt]);
    }
  }
  // epilogue: e1_pre = e + attn_out + bOe ; BN stats
#pragma unroll
  for (int nt=0; nt<8; nt++){
    float s1 = 0.f, s2 = 0.f;
#pragma unroll
    for (int r=0; r<4; r++){
      int row = crow + r, col = nt*16 + ccol;
      int ed = r0 + row;
      float val = 0.f;
      if (ed < M){
        val = a2[nt][r] + e[(size_t)ed * DIM + col] + bOe[col];
        e1_pre[(size_t)ed * DIM + col] = val;
      }
      s1 += val; s2 += val * val;
    }
    s1 += __shfl_xor(s1, 16); s1 += __shfl_xor(s1, 32);
    s2 += __shfl_xor(s2, 16); s2 += __shfl_xor(s2, 32);
    if (lane < 16){
      atomicAdd(&sStats[nt*16 + ccol], s1);
      atomicAdd(&sStats[128 + nt*16 + ccol], s2);
    }
  }
  __syncthreads();
  if (tid < 256) unsafeAtomicAdd(&stats[tid], sStats[tid]);
}

// ---------------- aggregation: one wave per node, CSR walk, no atomics ----------------
__global__ __launch_bounds__(512) void k_agg(
    const int* __restrict__ rowptr, const int* __restrict__ csr,
    const int* __restrict__ src, const float* __restrict__ envl,
    const float* __restrict__ sv, const bf16_t* __restrict__ V,
    bf16_t* __restrict__ vAttn, int M)
{
  const int wave = threadIdx.x >> 6, lane = threadIdx.x & 63;
  const int n = blockIdx.x * 8 + wave;
  if (n >= M) return;
  const int beg = rowptr[n], end = rowptr[n + 1];
  const int h = lane >> 3;           // head of cols (2*lane, 2*lane+1)
  float ax = 0.f, ay = 0.f, zacc = 0.f;
  for (int i = beg; i < end; i++){
    int eid = csr[i];
    int sn = src[eid];
    float s = sv[(size_t)eid * 8 + h];
    float env = envl[eid];
    const bf16x2 vv = *(const bf16x2*)(V + (size_t)sn * DIM + lane * 2);
    float w = env * s;
    ax += (float)vv[0] * w; ay += (float)vv[1] * w;
    zacc += s;
  }
  float inv = 1.f / (zacc + 1e-6f);
  bf16x2 o; o[0] = (bf16_t)(ax * inv); o[1] = (bf16_t)(ay * inv);
  *(bf16x2*)(vAttn + (size_t)n * DIM + lane * 2) = o;
}

// ---------------- node: v1_pre = v + v_attn@WO_v + bOv; stats ----------------
__global__ __launch_bounds__(512) void k_nodeout(
    const bf16_t* __restrict__ vAttn, const float* __restrict__ v,
    const char* __restrict__ imgWo, const float* __restrict__ bOv,
    float* __restrict__ v1_pre, float* __restrict__ stats, int M)
{
  __shared__ __align__(16) char sm[66560];
  char* sW = sm;
  char* sX = sm + 32768;
  float* sStats = (float*)(sm + 65536);
  const int tid = threadIdx.x, lane = tid & 63, wave = tid >> 6;
  const int r0 = blockIdx.x * 128;
  copy16(sW, imgWo, 32768);
  if (tid < 256) sStats[tid] = 0.f;
  for (int c = tid; c < 2048; c += 512){
    int row = c >> 4, kc = c & 15, grow = r0 + row;
    bf16x8 o;
    if (grow < M){
      o = *(const bf16x8*)(vAttn + (size_t)grow * DIM + kc * 8);
    } else {
#pragma unroll
      for (int j=0;j<8;j++) o[j] = (bf16_t)0.f;
    }
    *(bf16x8*)(sX + row*256 + swz(row, kc*16)) = o;
  }
  __syncthreads();
  const int rowA = wave*16 + (lane & 15);
  const int kb0 = (lane >> 4)*16;
  const f32x4 zero4 = {0.f,0.f,0.f,0.f};
  f32x4 acc[8];
#pragma unroll
  for (int i=0;i<8;i++) acc[i]=zero4;
#pragma unroll
  for (int ks=0;ks<4;ks++){
    bf16x8 a = lds_frag(sX, rowA, 256, ks*64+kb0);
#pragma unroll
    for (int nt=0;nt<8;nt++){
      int rn = nt*16 + (lane&15);
      bf16x8 b = lds_frag(sW, rn, 256, ks*64+kb0);
      acc[nt] = MFMA(a,b,acc[nt]);
    }
  }
  const int crow = wave*16 + (lane>>4)*4;
  const int ccol = lane & 15;
#pragma unroll
  for (int nt=0;nt<8;nt++){
    float s1=0.f, s2=0.f;
#pragma unroll
    for (int r=0;r<4;r++){
      int grow = r0 + crow + r, col = nt*16 + ccol;
      float val = 0.f;
      if (grow < M){
        val = acc[nt][r] + v[(size_t)grow*DIM + col] + bOv[col];
        v1_pre[(size_t)grow*DIM + col] = val;
      }
      s1 += val; s2 += val*val;
    }
    s1 += __shfl_xor(s1,16); s1 += __shfl_xor(s1,32);
    s2 += __shfl_xor(s2,16); s2 += __shfl_xor(s2,32);
    if (lane < 16){
      atomicAdd(&sStats[nt*16+ccol], s1);
      atomicAdd(&sStats[128+nt*16+ccol], s2);
    }
  }
  __syncthreads();
  if (tid < 256) unsafeAtomicAdd(&stats[tid], sStats[tid]);
}

// ---------------- fused FFN (weights in 32KB halves for 2-block occupancy) ----------------
__global__ __launch_bounds__(512) void k_ffn(
    float* __restrict__ xio, const float* __restrict__ ss1,
    const char* __restrict__ img1, const float* __restrict__ b1,
    const char* __restrict__ img2, const float* __restrict__ b2,
    float* __restrict__ stats2, int M)
{
  __shared__ __align__(16) char sm[66560];
  char* sX = sm;           // x1 tile (bf16), then relu(h half) tile
  char* sW = sm + 32768;   // W1h0, W1h1, W2h0, W2h1
  float* sStats = (float*)(sm + 65536);
  const int tid = threadIdx.x, lane = tid & 63, wave = tid >> 6;
  const int r0 = blockIdx.x * 128;
  copy16(sW, img1, 32768);
  if (tid < 256) sStats[tid] = 0.f;
  for (int c = tid; c < 2048; c += 512){
    int row = c >> 4, kc = c & 15, grow = r0 + row;
    float f[8];
    if (grow < M){
      const float4* p = (const float4*)(xio + (size_t)grow*DIM + kc*8);
      float4 u0 = p[0], u1 = p[1];
      f[0]=u0.x; f[1]=u0.y; f[2]=u0.z; f[3]=u0.w;
      f[4]=u1.x; f[5]=u1.y; f[6]=u1.z; f[7]=u1.w;
#pragma unroll
      for (int j=0;j<8;j++){ int col = kc*8 + j; f[j] = f[j]*ss1[col] + ss1[128+col]; }
    } else {
#pragma unroll
      for (int j=0;j<8;j++) f[j]=0.f;
    }
    bf16x8 o;
#pragma unroll
    for (int j=0;j<8;j++) o[j]=(bf16_t)f[j];
    *(bf16x8*)(sX + row*256 + swz(row, kc*16)) = o;
  }
  __syncthreads();
  const int rowA = wave*16 + (lane & 63 & 15);
  const int kb0 = (lane >> 4) * 16;
  const f32x4 zero4 = {0.f,0.f,0.f,0.f};
  f32x4 h[16];
#pragma unroll
  for (int i=0;i<16;i++) h[i]=zero4;
  // GEMM1 half0 (hidden cols 0..127)
#pragma unroll
  for (int ks=0;ks<4;ks++){
    bf16x8 a = lds_frag(sX, rowA, 256, ks*64+kb0);
#pragma unroll
    for (int nt=0;nt<8;nt++){
      int rn = nt*16 + (lane&15);
      bf16x8 b = lds_frag(sW, rn, 256, ks*64+kb0);
      h[nt] = MFMA(a,b,h[nt]);
    }
  }
  __syncthreads();
  copy16(sW, img1 + 32768, 32768);   // W1 half1
  __syncthreads();
#pragma unroll
  for (int ks=0;ks<4;ks++){
    bf16x8 a = lds_frag(sX, rowA, 256, ks*64+kb0);
#pragma unroll
    for (int nt=0;nt<8;nt++){
      int rn = nt*16 + (lane&15);
      bf16x8 b = lds_frag(sW, rn, 256, ks*64+kb0);
      h[8+nt] = MFMA(a,b,h[8+nt]);
    }
  }
  __syncthreads();    // done with sX (x tile) and sW
  const int crow = wave*16 + (lane>>4)*4;
  const int ccol = lane & 15;
  f32x4 o2[8];
#pragma unroll
  for (int i=0;i<8;i++) o2[i]=zero4;
#pragma unroll
  for (int half = 0; half < 2; half++){
    // write relu(h half) into sX
#pragma unroll
    for (int nt=0;nt<8;nt++)
#pragma unroll
      for (int r=0;r<4;r++){
        int row = crow + r, col = nt*16 + ccol;
        float hv = fmaxf(h[half*8+nt][r] + b1[half*128 + col], 0.f);
        *(bf16_t*)(sX + row*256 + swz(row, col*2)) = (bf16_t)hv;
      }
    copy_half(sW, img2, half * 256);   // W2 rows, k-half
    __syncthreads();
#pragma unroll
    for (int ks=0;ks<4;ks++){
      bf16x8 a = lds_frag(sX, rowA, 256, ks*64+kb0);
#pragma unroll
      for (int nt=0;nt<8;nt++){
        int rn = nt*16 + (lane&15);
        bf16x8 b = lds_frag(sW, rn, 256, ks*64+kb0);
        o2[nt] = MFMA(a,b,o2[nt]);
      }
    }
    __syncthreads();
  }
#pragma unroll
  for (int nt=0;nt<8;nt++){
    float s1=0.f, s2=0.f;
#pragma unroll
    for (int r=0;r<4;r++){
      int row = crow + r, col = nt*16 + ccol;
      int grow = r0 + row;
      float val = 0.f;
      if (grow < M){
        float xp = xio[(size_t)grow*DIM + col];
        float x1 = xp*ss1[col] + ss1[128+col];
        val = x1 + o2[nt][r] + b2[col];
        xio[(size_t)grow*DIM + col] = val;
      }
      s1 += val; s2 += val*val;
    }
    s1 += __shfl_xor(s1,16); s1 += __shfl_xor(s1,32);
    s2 += __shfl_xor(s2,16); s2 += __shfl_xor(s2,32);
    if (lane < 16){
      atomicAdd(&sStats[nt*16+ccol], s1);
      atomicAdd(&sStats[128+nt*16+ccol], s2);
    }
  }
  __syncthreads();
  if (tid < 256) unsafeAtomicAdd(&stats2[tid], sStats[tid]);
}

// ---------------- stats -> scale/shift ----------------
struct FinArgs { const float* st; const float* g; const float* b; float* ss; float invM; };

__global__ void k_finstats(FinArgs a0, FinArgs a1){
  FinArgs a = (blockIdx.x == 0) ? a0 : a1;
  int c = threadIdx.x;
  float mean = a.st[c] * a.invM;
  float var  = a.st[128 + c] * a.invM - mean * mean;
  float scl  = a.g[c] * rsqrtf(var + 1e-5f);
  a.ss[c] = scl;
  a.ss[128 + c] = a.b[c] - mean * scl;
}

// ---------------- in-place normalize ----------------
__global__ void k_norm(float* __restrict__ x, const float* __restrict__ ss, long long n4){
  for (long long i = (long long)blockIdx.x * blockDim.x + threadIdx.x; i < n4;
       i += (long long)gridDim.x * blockDim.x){
    float4* p = (float4*)x + i;
    float4 t = *p;
    int c0 = (int)((i * 4) & 127);
    t.x = t.x * ss[c0]     + ss[128 + c0];
    t.y = t.y * ss[c0 + 1] + ss[128 + c0 + 1];
    t.z = t.z * ss[c0 + 2] + ss[128 + c0 + 2];
    t.w = t.w * ss[c0 + 3] + ss[128 + c0 + 3];
    *p = t;
  }
}

extern "C" void kernel_launch(void* const* d_in, const int* in_sizes, int n_in,
                              void* d_out, int out_size, void* d_ws, size_t ws_size,
                              hipStream_t stream)
{
  const float* v    = (const float*)d_in[0];
  const float* e    = (const float*)d_in[1];
  const float* envl = (const float*)d_in[2];
  const int*   src  = (const int*)d_in[3];
  const int*   dst  = (const int*)d_in[4];
  const float* bOv  = (const float*)d_in[10];
  const float* bOe  = (const float*)d_in[12];
  const float* g1v  = (const float*)d_in[13];
  const float* b1vn = (const float*)d_in[14];
  const float* g1e  = (const float*)d_in[15];
  const float* b1en = (const float*)d_in[16];
  const float* g2v  = (const float*)d_in[17];
  const float* b2vn = (const float*)d_in[18];
  const float* g2e  = (const float*)d_in[19];
  const float* b2en = (const float*)d_in[20];
  const float* b1vf = (const float*)d_in[22];
  const float* b2vf = (const float*)d_in[24];
  const float* b1ef = (const float*)d_in[26];
  const float* b2ef = (const float*)d_in[28];

  float* out_v = (float*)d_out;
  float* out_e = out_v + (size_t)N_NODES * DIM;

  char* ws = (char*)d_ws;
  const size_t IMG_OFF = 0;                        // 458752 B of bf16 weight images
  const size_t QB_OFF  = 458752;                   // bf16 Q  (N*128*2 = 12.8MB)
  const size_t KB_OFF  = QB_OFF  + 12800000;       // bf16 K
  const size_t VB_OFF  = KB_OFF  + 12800000;       // bf16 V
  const size_t VA_OFF  = VB_OFF  + 12800000;       // bf16 vAttn
  const size_t SV_OFF  = VA_OFF  + 12800000;       // s per edge per head: E*8*4 = 16MB
  const size_t CSR_OFF = SV_OFF  + 16000000;       // E ints
  const size_t RP_OFF  = CSR_OFF + 2000000;        // N+1 ints
  const size_t WP_OFF  = RP_OFF  + 200016;         // N ints
  const size_t CNT_OFF = WP_OFF  + 200000;         // N ints (memset 0)
  const size_t ST_OFF  = CNT_OFF + 200000;         // 1024 f (memset 0)
  const size_t SS_OFF  = ST_OFF  + 4096;           // 1024 f

  char*   img   = ws + IMG_OFF;
  bf16_t* Qb    = (bf16_t*)(ws + QB_OFF);
  bf16_t* Kb    = (bf16_t*)(ws + KB_OFF);
  bf16_t* Vb    = (bf16_t*)(ws + VB_OFF);
  bf16_t* vAttn = (bf16_t*)(ws + VA_OFF);
  float*  svp   = (float*)(ws + SV_OFF);
  int*    csr   = (int*)(ws + CSR_OFF);
  int*    rowp  = (int*)(ws + RP_OFF);
  int*    wpp   = (int*)(ws + WP_OFF);
  int*    cnt   = (int*)(ws + CNT_OFF);
  float*  st    = (float*)(ws + ST_OFF);
  float*  ssb   = (float*)(ws + SS_OFF);
  float* st_e1 = st;        float* st_v1 = st + 256;
  float* st_v2 = st + 512;  float* st_e2 = st + 768;
  float* ss_v1 = ssb;       float* ss_e1 = ssb + 256;
  float* ss_v2 = ssb + 512; float* ss_e2 = ssb + 768;

  // zero counters + stats (contiguous)
  (void)hipMemsetAsync(ws + CNT_OFF, 0, 200000 + 4096, stream);

  WPrep wp;
  const int wid[10]   = {5,6,7,8,9,11,21,23,25,27};
  const int Ks[10]    = {128,128,128,128,128,128,128,256,128,256};
  const int Ns[10]    = {128,128,128,128,128,128,256,128,256,128};
  const int modes[10] = {0,0,0,1,0,2,0,0,0,0};   // We: n-perm; WO_e: k-perm
  int cum = 0, off = 0;
  for (int i = 0; i < 10; i++){
    wp.w[i] = (const float*)d_in[wid[i]];
    wp.Kd[i] = Ks[i]; wp.Nd[i] = Ns[i];
    wp.off[i] = off; wp.cum[i] = cum; wp.mode[i] = modes[i];
    off += Ks[i]*Ns[i]*2; cum += Ks[i]*Ns[i];
  }
  k_wprep<<<896, 256, 0, stream>>>(wp, img, cum);

  // CSR build (independent of QKV)
  k_count<<<1954, 256, 0, stream>>>(dst, cnt);
  k_scan<<<1, 1024, 0, stream>>>(cnt, rowp, wpp);
  k_fill<<<1954, 256, 0, stream>>>(dst, wpp, csr);

  k_qkv<<<391, 512, 0, stream>>>(v, img, Qb, Kb, Vb, N_NODES);

  k_edge<<<3907, 512, 0, stream>>>(e, src, dst, Qb, Kb,
                                   img + 98304 /*We*/, img + 163840 /*WO_e*/, bOe,
                                   out_e, svp, st_e1, N_EDGES);

  k_agg<<<6250, 512, 0, stream>>>(rowp, csr, src, envl, svp, Vb, vAttn, N_NODES);

  k_nodeout<<<391, 512, 0, stream>>>(vAttn, v, img + 131072 /*WO_v*/, bOv,
                                     out_v, st_v1, N_NODES);

  {
    FinArgs fv{st_v1, g1v, b1vn, ss_v1, 1.f / N_NODES};
    FinArgs fe{st_e1, g1e, b1en, ss_e1, 1.f / N_EDGES};
    k_finstats<<<2, 128, 0, stream>>>(fv, fe);
  }

  k_ffn<<<391, 512, 0, stream>>>(out_v, ss_v1, img + 196608 /*W1v*/, b1vf,
                                 img + 262144 /*W2v*/, b2vf, st_v2, N_NODES);
  k_ffn<<<3907, 512, 0, stream>>>(out_e, ss_e1, img + 327680 /*W1e*/, b1ef,
                                  img + 393216 /*W2e*/, b2ef, st_e2, N_EDGES);

  {
    FinArgs fv{st_v2, g2v, b2vn, ss_v2, 1.f / N_NODES};
    FinArgs fe{st_e2, g2e, b2en, ss_e2, 1.f / N_EDGES};
    k_finstats<<<2, 128, 0, stream>>>(fv, fe);
  }

  k_norm<<<2048, 256, 0, stream>>>(out_v, ss_v2, (long long)(N_NODES) * DIM / 4);
  k_norm<<<4096, 256, 0, stream>>>(out_e, ss_e2, (long long)(N_EDGES) * DIM / 4);
}

// Round 4
// 844.289 us; speedup vs baseline: 4.9886x; 1.1387x over previous
//
#include <hip/hip_runtime.h>
#include <hip/hip_bf16.h>

#define N_NODES 50000
#define N_EDGES 500000
#define DIM 128

typedef __bf16 bf16_t;
typedef __bf16 bf16x8 __attribute__((ext_vector_type(8)));
typedef __bf16 bf16x2 __attribute__((ext_vector_type(2)));
typedef float f32x4 __attribute__((ext_vector_type(4)));

#define MFMA(a,b,c) __builtin_amdgcn_mfma_f32_16x16x32_bf16((a),(b),(c),0,0,0)

// XOR swizzle (guide G4): kills 32-way bank conflicts for 256B/512B-stride rows
__device__ __forceinline__ int swz(int row, int kbyte){ return kbyte ^ ((row & 7) << 4); }
// full 4-bit row swizzle for the h buffer (256B rows, 16-row period)
__device__ __forceinline__ int hswz(int row, int kbyte){ return kbyte ^ ((row & 15) << 4); }

__device__ __forceinline__ bf16x8 lds_frag(const char* s, int row, int rowb, int kbyte){
  return *(const bf16x8*)(s + row * rowb + swz(row, kbyte));
}

__device__ __forceinline__ void copy16(char* dst, const char* __restrict__ src, int bytes){
  for (int o = threadIdx.x * 16; o < bytes; o += blockDim.x * 16)
    *(f32x4*)(dst + o) = *(const f32x4*)(src + o);
}

// ---------------- weight prep: f32 [K][N] -> bf16 transposed swizzled image [n][k] ----------------
// mode 1: permute output-col n -> ((n&7)<<4)|(n>>3)    (We, N=128: contiguous logical cols/thread)
// mode 2: permute K-row k the same way                  (WO_e: matches score's physical K order)
// mode 3: permute output-col n -> ((n&15)<<4)|(n>>4)    (W1, N=256: contiguous logical hcols/thread)
struct WPrep {
  const float* w[10];
  int Kd[10], Nd[10], off[10], cum[10], mode[10];
};

__global__ void k_wprep(WPrep d, char* img, int total){
  for (int idx = blockIdx.x * blockDim.x + threadIdx.x; idx < total; idx += gridDim.x * blockDim.x){
    int i = 0;
#pragma unroll
    for (int j = 1; j < 10; j++) if (idx >= d.cum[j]) i = j;
    int loc = idx - d.cum[i];
    int K = d.Kd[i], N = d.Nd[i];
    int n = loc / K, k = loc - n * K;
    float val = d.w[i][(size_t)k * N + n];
    int nn = n, kk = k;
    if (d.mode[i] == 1) nn = ((n & 7) << 4) | (n >> 3);
    if (d.mode[i] == 2) kk = ((k & 7) << 4) | (k >> 3);
    if (d.mode[i] == 3) nn = ((n & 15) << 4) | (n >> 4);
    *(bf16_t*)(img + d.off[i] + nn * (K * 2) + swz(nn, kk * 2)) = (bf16_t)val;
  }
}

// ---------------- CSR build ----------------
__global__ void k_count(const int* __restrict__ dst, int* __restrict__ cnt){
  int i = blockIdx.x * blockDim.x + threadIdx.x;
  if (i < N_EDGES) atomicAdd(&cnt[dst[i]], 1);
}

__global__ __launch_bounds__(1024) void k_scan(const int* __restrict__ cnt,
                                               int* __restrict__ rowptr, int* __restrict__ wp){
  __shared__ int wsum[16];
  __shared__ int wpre[16];
  __shared__ int scarry;
  const int tid = threadIdx.x, lane = tid & 63, wv = tid >> 6;
  if (tid == 0) scarry = 0;
  for (int base = 0; base < N_NODES; base += 8192){
    int i0 = base + tid * 8;
    int v[8], p[8];
    int tsum = 0;
#pragma unroll
    for (int j = 0; j < 8; j++){
      int idx = i0 + j;
      v[j] = (idx < N_NODES) ? cnt[idx] : 0;
      p[j] = tsum; tsum += v[j];
    }
    int x = tsum;
#pragma unroll
    for (int off = 1; off < 64; off <<= 1){
      int t = __shfl_up(x, off);
      if (lane >= off) x += t;
    }
    if (lane == 63) wsum[wv] = x;
    __syncthreads();
    if (tid == 0){
      int run = scarry;
#pragma unroll
      for (int j = 0; j < 16; j++){ int t = wsum[j]; wpre[j] = run; run += t; }
      scarry = run;
    }
    __syncthreads();
    int texcl = wpre[wv] + x - tsum;
#pragma unroll
    for (int j = 0; j < 8; j++){
      int idx = i0 + j;
      if (idx < N_NODES){ rowptr[idx] = texcl + p[j]; wp[idx] = texcl + p[j]; }
    }
  }
  __syncthreads();
  if (tid == 0) rowptr[N_NODES] = scarry;
}

__global__ void k_fill(const int* __restrict__ dst, int* __restrict__ wp, int* __restrict__ csr){
  int i = blockIdx.x * blockDim.x + threadIdx.x;
  if (i < N_EDGES){
    int p = atomicAdd(&wp[dst[i]], 1);
    csr[p] = i;
  }
}

// ---------------- QKV: [M,128] @ 3x [128,128] -> bf16 outputs ----------------
__global__ __launch_bounds__(512) void k_qkv(
    const float* __restrict__ v, const char* __restrict__ img,
    bf16_t* __restrict__ Q, bf16_t* __restrict__ K, bf16_t* __restrict__ V, int M)
{
  __shared__ __align__(16) char sm[65536];
  char* sX = sm;
  char* sW = sm + 32768;
  const int tid = threadIdx.x, lane = tid & 63, wave = tid >> 6;
  const int r0 = blockIdx.x * 128;
  for (int c = tid; c < 2048; c += 512){
    int row = c >> 4, kc = c & 15, grow = r0 + row;
    float f[8];
    if (grow < M){
      const float4* p = (const float4*)(v + (size_t)grow * DIM + kc * 8);
      float4 u0 = p[0], u1 = p[1];
      f[0]=u0.x; f[1]=u0.y; f[2]=u0.z; f[3]=u0.w;
      f[4]=u1.x; f[5]=u1.y; f[6]=u1.z; f[7]=u1.w;
    } else {
#pragma unroll
      for (int j=0;j<8;j++) f[j] = 0.f;
    }
    bf16x8 o;
#pragma unroll
    for (int j=0;j<8;j++) o[j] = (bf16_t)f[j];
    *(bf16x8*)(sX + row * 256 + swz(row, kc * 16)) = o;
  }
  const int rowA = wave * 16 + (lane & 15);
  const int kb0 = (lane >> 4) * 16;
  const int crow = wave*16 + (lane >> 4)*4;
  const int ccol = lane & 15;
  const f32x4 zero4 = {0.f, 0.f, 0.f, 0.f};
#pragma unroll
  for (int w3 = 0; w3 < 3; w3++){
    __syncthreads();            // staging done / prev GEMM done with sW
    copy16(sW, img + w3 * 32768, 32768);
    __syncthreads();
    f32x4 acc[8];
#pragma unroll
    for (int b=0;b<8;b++) acc[b] = zero4;
#pragma unroll
    for (int ks=0; ks<4; ks++){
      bf16x8 a = lds_frag(sX, rowA, 256, ks*64 + kb0);
#pragma unroll
      for (int nt=0; nt<8; nt++){
        int rn = nt*16 + (lane & 15);
        bf16x8 b = lds_frag(sW, rn, 256, ks*64 + kb0);
        acc[nt] = MFMA(a, b, acc[nt]);
      }
    }
    bf16_t* o = (w3 == 0) ? Q : ((w3 == 1) ? K : V);
#pragma unroll
    for (int nt=0; nt<8; nt++)
#pragma unroll
      for (int r=0; r<4; r++){
        int grow = r0 + crow + r;
        if (grow < M) o[(size_t)grow * DIM + nt*16 + ccol] = (bf16_t)acc[nt][r];
      }
  }
}

// ---------------- fused edge attention ----------------
__global__ __launch_bounds__(512, 4) void k_edge(
    const float* __restrict__ e,
    const int* __restrict__ src, const int* __restrict__ dst,
    const bf16_t* __restrict__ Qb, const bf16_t* __restrict__ Kb,
    const char* __restrict__ imgWe, const char* __restrict__ imgWo,
    const float* __restrict__ bOe,
    float* __restrict__ e1_pre, float* __restrict__ sv,
    float* __restrict__ stats, int M)
{
  __shared__ __align__(16) char sm[66560];
  char* sW = sm;                          // 32KB: We then WO_e
  char* sX = sm + 32768;                  // 32KB: e tile, then score
  float* sStats = (float*)(sm + 65536);   // 256 f
  const int tid = threadIdx.x, lane = tid & 63, wave = tid >> 6;
  const int r0 = blockIdx.x * 128;
  const int crow = wave*16 + (lane >> 4)*4;
  const int ccol = lane & 15;
  // prefetch K[src]/Q[dst] fragments (in flight through staging + GEMM1)
  bf16x8 Kg[4], Qg[4];
#pragma unroll
  for (int r=0;r<4;r++){
    int ed = r0 + crow + r; if (ed >= M) ed = M - 1;
    int sn = src[ed], dn = dst[ed];
    Kg[r] = *(const bf16x8*)(Kb + (size_t)sn * DIM + ccol * 8);
    Qg[r] = *(const bf16x8*)(Qb + (size_t)dn * DIM + ccol * 8);
  }
  copy16(sW, imgWe, 32768);
  if (tid < 256) sStats[tid] = 0.f;
  for (int c = tid; c < 2048; c += 512){
    int row = c >> 4, kc = c & 15, grow = r0 + row;
    float f[8];
    if (grow < M){
      const float4* p = (const float4*)(e + (size_t)grow * DIM + kc * 8);
      float4 u0 = p[0], u1 = p[1];
      f[0]=u0.x; f[1]=u0.y; f[2]=u0.z; f[3]=u0.w;
      f[4]=u1.x; f[5]=u1.y; f[6]=u1.z; f[7]=u1.w;
    } else {
#pragma unroll
      for (int j=0;j<8;j++) f[j] = 0.f;
    }
    bf16x8 o;
#pragma unroll
    for (int j=0;j<8;j++) o[j] = (bf16_t)f[j];
    *(bf16x8*)(sX + row * 256 + swz(row, kc * 16)) = o;
  }
  __syncthreads();
  const int rowA = wave * 16 + (lane & 15);
  const int kb0 = (lane >> 4) * 16;
  const f32x4 zero4 = {0.f,0.f,0.f,0.f};
  f32x4 pe[8];
#pragma unroll
  for (int i=0;i<8;i++) pe[i] = zero4;
#pragma unroll
  for (int ks=0; ks<4; ks++){
    bf16x8 a = lds_frag(sX, rowA, 256, ks*64 + kb0);
#pragma unroll
    for (int nt=0; nt<8; nt++){
      int rn = nt*16 + (lane & 15);
      bf16x8 b = lds_frag(sW, rn, 256, ks*64 + kb0);
      pe[nt] = MFMA(a, b, pe[nt]);
    }
  }
  __syncthreads();   // done reading sX (e tile) and sW (We)
  copy16(sW, imgWo, 32768);               // WO_e into the same buffer (overlaps score phase)
  // score in registers; pe[nt][r] * K/Q logical col ccol*8+nt
  float hs[4] = {0.f, 0.f, 0.f, 0.f};
#pragma unroll
  for (int nt=0; nt<8; nt++)
#pragma unroll
    for (int r=0;r<4;r++){
      float sc = pe[nt][r] * 0.25f * (float)Kg[r][nt] * (float)Qg[r][nt];
      int row = crow + r;
      *(bf16_t*)(sX + row*256 + swz(row, (nt*16 + ccol)*2)) = (bf16_t)sc;
      hs[r] += sc;
    }
#pragma unroll
  for (int r=0;r<4;r++){
    float t = hs[r] + __shfl_xor(hs[r], 1);   // pair covers the full 16-col head
    int ed = r0 + crow + r;
    if (!(ccol & 1) && ed < M)
      sv[(size_t)ed*8 + (ccol >> 1)] = __expf(fminf(5.f, fmaxf(-5.f, t)));
  }
  __syncthreads();
  // GEMM2: e_attn @ WO_e (K-permuted image matches score's physical order)
  f32x4 a2[8];
#pragma unroll
  for (int i=0;i<8;i++) a2[i] = zero4;
#pragma unroll
  for (int ks=0; ks<4; ks++){
    bf16x8 a = lds_frag(sX, rowA, 256, ks*64 + kb0);
#pragma unroll
    for (int nt=0; nt<8; nt++){
      int rn = nt*16 + (lane & 15);
      bf16x8 b = lds_frag(sW, rn, 256, ks*64 + kb0);
      a2[nt] = MFMA(a, b, a2[nt]);
    }
  }
  // epilogue: e1_pre = e + attn_out + bOe ; BN stats
#pragma unroll
  for (int nt=0; nt<8; nt++){
    float s1 = 0.f, s2 = 0.f;
#pragma unroll
    for (int r=0; r<4; r++){
      int row = crow + r, col = nt*16 + ccol;
      int ed = r0 + row;
      float val = 0.f;
      if (ed < M){
        val = a2[nt][r] + e[(size_t)ed * DIM + col] + bOe[col];
        e1_pre[(size_t)ed * DIM + col] = val;
      }
      s1 += val; s2 += val * val;
    }
    s1 += __shfl_xor(s1, 16); s1 += __shfl_xor(s1, 32);
    s2 += __shfl_xor(s2, 16); s2 += __shfl_xor(s2, 32);
    if (lane < 16){
      atomicAdd(&sStats[nt*16 + ccol], s1);
      atomicAdd(&sStats[128 + nt*16 + ccol], s2);
    }
  }
  __syncthreads();
  if (tid < 256) unsafeAtomicAdd(&stats[tid], sStats[tid]);
}

// ---------------- aggregation: one wave per node, CSR walk, no atomics ----------------
__global__ __launch_bounds__(512) void k_agg(
    const int* __restrict__ rowptr, const int* __restrict__ csr,
    const int* __restrict__ src, const float* __restrict__ envl,
    const float* __restrict__ sv, const bf16_t* __restrict__ V,
    bf16_t* __restrict__ vAttn, int M)
{
  const int wave = threadIdx.x >> 6, lane = threadIdx.x & 63;
  const int n = blockIdx.x * 8 + wave;
  if (n >= M) return;
  const int beg = rowptr[n], end = rowptr[n + 1];
  const int h = lane >> 3;           // head of cols (2*lane, 2*lane+1)
  float ax = 0.f, ay = 0.f, zacc = 0.f;
  for (int i = beg; i < end; i++){
    int eid = csr[i];
    int sn = src[eid];
    float s = sv[(size_t)eid * 8 + h];
    float env = envl[eid];
    const bf16x2 vv = *(const bf16x2*)(V + (size_t)sn * DIM + lane * 2);
    float w = env * s;
    ax += (float)vv[0] * w; ay += (float)vv[1] * w;
    zacc += s;
  }
  float inv = 1.f / (zacc + 1e-6f);
  bf16x2 o; o[0] = (bf16_t)(ax * inv); o[1] = (bf16_t)(ay * inv);
  *(bf16x2*)(vAttn + (size_t)n * DIM + lane * 2) = o;
}

// ---------------- node: v1_pre = v + v_attn@WO_v + bOv; stats ----------------
__global__ __launch_bounds__(512) void k_nodeout(
    const bf16_t* __restrict__ vAttn, const float* __restrict__ v,
    const char* __restrict__ imgWo, const float* __restrict__ bOv,
    float* __restrict__ v1_pre, float* __restrict__ stats, int M)
{
  __shared__ __align__(16) char sm[66560];
  char* sW = sm;
  char* sX = sm + 32768;
  float* sStats = (float*)(sm + 65536);
  const int tid = threadIdx.x, lane = tid & 63, wave = tid >> 6;
  const int r0 = blockIdx.x * 128;
  copy16(sW, imgWo, 32768);
  if (tid < 256) sStats[tid] = 0.f;
  for (int c = tid; c < 2048; c += 512){
    int row = c >> 4, kc = c & 15, grow = r0 + row;
    bf16x8 o;
    if (grow < M){
      o = *(const bf16x8*)(vAttn + (size_t)grow * DIM + kc * 8);
    } else {
#pragma unroll
      for (int j=0;j<8;j++) o[j] = (bf16_t)0.f;
    }
    *(bf16x8*)(sX + row*256 + swz(row, kc*16)) = o;
  }
  __syncthreads();
  const int rowA = wave*16 + (lane & 15);
  const int kb0 = (lane >> 4)*16;
  const f32x4 zero4 = {0.f,0.f,0.f,0.f};
  f32x4 acc[8];
#pragma unroll
  for (int i=0;i<8;i++) acc[i]=zero4;
#pragma unroll
  for (int ks=0;ks<4;ks++){
    bf16x8 a = lds_frag(sX, rowA, 256, ks*64+kb0);
#pragma unroll
    for (int nt=0;nt<8;nt++){
      int rn = nt*16 + (lane&15);
      bf16x8 b = lds_frag(sW, rn, 256, ks*64+kb0);
      acc[nt] = MFMA(a,b,acc[nt]);
    }
  }
  const int crow = wave*16 + (lane>>4)*4;
  const int ccol = lane & 15;
#pragma unroll
  for (int nt=0;nt<8;nt++){
    float s1=0.f, s2=0.f;
#pragma unroll
    for (int r=0;r<4;r++){
      int grow = r0 + crow + r, col = nt*16 + ccol;
      float val = 0.f;
      if (grow < M){
        val = acc[nt][r] + v[(size_t)grow*DIM + col] + bOv[col];
        v1_pre[(size_t)grow*DIM + col] = val;
      }
      s1 += val; s2 += val*val;
    }
    s1 += __shfl_xor(s1,16); s1 += __shfl_xor(s1,32);
    s2 += __shfl_xor(s2,16); s2 += __shfl_xor(s2,32);
    if (lane < 16){
      atomicAdd(&sStats[nt*16+ccol], s1);
      atomicAdd(&sStats[128+nt*16+ccol], s2);
    }
  }
  __syncthreads();
  if (tid < 256) unsafeAtomicAdd(&stats[tid], sStats[tid]);
}

// ---------------- fused FFN ----------------
// W1 image col-permuted (mode 3): C element (nt,ccol) = logical hcol ccol*16+nt (+8 for half1)
// -> h kept as bf16 in VGPRs (32 regs, not 96 AGPRs) -> 2 blocks/CU.
// h staged to LDS per k-half as 8x ds_write_b128 with full 4-bit row swizzle; W2 natural k-order.
// All weight copies are reg-staged (issue loads during previous MFMA phase, ds_write after barrier).
__global__ __launch_bounds__(512, 4) void k_ffn(
    float* __restrict__ xio, const float* __restrict__ ss1,
    const char* __restrict__ img1, const float* __restrict__ b1,
    const char* __restrict__ img2, const float* __restrict__ b2,
    float* __restrict__ stats2, int M)
{
  __shared__ __align__(16) char sm[66560];
  char* sA = sm;           // x1 tile (bf16); later h halves (hswz layout)
  char* sB = sm + 32768;   // W1h0, W1h1, W2k0, W2k1
  float* sStats = (float*)(sm + 65536);
  const int tid = threadIdx.x, lane = tid & 63, wave = tid >> 6;
  const int r0 = blockIdx.x * 128;
  const int rowA = wave*16 + (lane & 15);
  const int kb0 = (lane >> 4) * 16;
  const int crow = wave*16 + (lane >> 4)*4;
  const int ccol = lane & 15;
  const f32x4 zero4 = {0.f,0.f,0.f,0.f};

  // biases for this thread's 16 contiguous logical hcols
  const float4* bq = (const float4*)(b1 + ccol * 16);
  float4 bq0 = bq[0], bq1 = bq[1], bq2 = bq[2], bq3 = bq[3];

  // phase 1: stage x1 tile + W1 half0
  copy16(sB, img1, 32768);
  if (tid < 256) sStats[tid] = 0.f;
  for (int c = tid; c < 2048; c += 512){
    int row = c >> 4, kc = c & 15, grow = r0 + row;
    float f[8];
    if (grow < M){
      const float4* p = (const float4*)(xio + (size_t)grow*DIM + kc*8);
      float4 u0 = p[0], u1 = p[1];
      f[0]=u0.x; f[1]=u0.y; f[2]=u0.z; f[3]=u0.w;
      f[4]=u1.x; f[5]=u1.y; f[6]=u1.z; f[7]=u1.w;
#pragma unroll
      for (int j=0;j<8;j++){ int col = kc*8 + j; f[j] = f[j]*ss1[col] + ss1[128+col]; }
    } else {
#pragma unroll
      for (int j=0;j<8;j++) f[j]=0.f;
    }
    bf16x8 o;
#pragma unroll
    for (int j=0;j<8;j++) o[j]=(bf16_t)f[j];
    *(bf16x8*)(sA + row*256 + swz(row, kc*16)) = o;
  }
  __syncthreads();

  bf16x8 hreg[8];   // [r] = half0 hcols (nt 0..7), [4+r] = half1 (nt 8..15)
  f32x4 wbuf[4];    // reg-staged next weight chunk

  // phase 2: GEMM1a (+ issue W1 half1 loads)
#pragma unroll
  for (int i=0;i<4;i++) wbuf[i] = *(const f32x4*)(img1 + 32768 + tid*16 + i*8192);
  {
    f32x4 acc[8];
#pragma unroll
    for (int i=0;i<8;i++) acc[i]=zero4;
#pragma unroll
    for (int ks=0;ks<4;ks++){
      bf16x8 a = lds_frag(sA, rowA, 256, ks*64+kb0);
#pragma unroll
      for (int nt=0;nt<8;nt++){
        int rn = nt*16 + (lane&15);
        bf16x8 b = lds_frag(sB, rn, 256, ks*64+kb0);
        acc[nt] = MFMA(a,b,acc[nt]);
      }
    }
    // logical hcol = ccol*16 + nt ; bias bq[nt>>2][nt&3]
#pragma unroll
    for (int r=0;r<4;r++){
      bf16x8 t;
      t[0]=(bf16_t)fmaxf(acc[0][r]+bq0.x,0.f); t[1]=(bf16_t)fmaxf(acc[1][r]+bq0.y,0.f);
      t[2]=(bf16_t)fmaxf(acc[2][r]+bq0.z,0.f); t[3]=(bf16_t)fmaxf(acc[3][r]+bq0.w,0.f);
      t[4]=(bf16_t)fmaxf(acc[4][r]+bq1.x,0.f); t[5]=(bf16_t)fmaxf(acc[5][r]+bq1.y,0.f);
      t[6]=(bf16_t)fmaxf(acc[6][r]+bq1.z,0.f); t[7]=(bf16_t)fmaxf(acc[7][r]+bq1.w,0.f);
      hreg[r] = t;
    }
  }
  __syncthreads();
  // phase 3: write W1 half1
#pragma unroll
  for (int i=0;i<4;i++) *(f32x4*)(sB + tid*16 + i*8192) = wbuf[i];
  __syncthreads();
  // phase 4: GEMM1b (+ issue W2 k-half0 loads)
#pragma unroll
  for (int i=0;i<4;i++){
    int o = tid*16 + i*8192;
    wbuf[i] = *(const f32x4*)(img2 + (o >> 8)*512 + (o & 255));
  }
  {
    f32x4 acc[8];
#pragma unroll
    for (int i=0;i<8;i++) acc[i]=zero4;
#pragma unroll
    for (int ks=0;ks<4;ks++){
      bf16x8 a = lds_frag(sA, rowA, 256, ks*64+kb0);
#pragma unroll
      for (int nt=0;nt<8;nt++){
        int rn = nt*16 + (lane&15);
        bf16x8 b = lds_frag(sB, rn, 256, ks*64+kb0);
        acc[nt] = MFMA(a,b,acc[nt]);
      }
    }
    // logical hcol = ccol*16 + 8 + nt
#pragma unroll
    for (int r=0;r<4;r++){
      bf16x8 t;
      t[0]=(bf16_t)fmaxf(acc[0][r]+bq2.x,0.f); t[1]=(bf16_t)fmaxf(acc[1][r]+bq2.y,0.f);
      t[2]=(bf16_t)fmaxf(acc[2][r]+bq2.z,0.f); t[3]=(bf16_t)fmaxf(acc[3][r]+bq2.w,0.f);
      t[4]=(bf16_t)fmaxf(acc[4][r]+bq3.x,0.f); t[5]=(bf16_t)fmaxf(acc[5][r]+bq3.y,0.f);
      t[6]=(bf16_t)fmaxf(acc[6][r]+bq3.z,0.f); t[7]=(bf16_t)fmaxf(acc[7][r]+bq3.w,0.f);
      hreg[4+r] = t;
    }
  }
  __syncthreads();   // sA (x tile) and sB free

  f32x4 o2[8];
#pragma unroll
  for (int i=0;i<8;i++) o2[i]=zero4;

#pragma unroll
  for (int half = 0; half < 2; half++){
    // write h k-half into sA (hswz layout, rows 256B of 128 hcols):
    // logical hcol in [half*128, half*128+128) <=> (ccol>>3) == half
    if ((ccol >> 3) == half){
      int cb = (ccol & 7) * 32;
#pragma unroll
      for (int r=0;r<4;r++){
        int row = crow + r;
        *(bf16x8*)(sA + row*256 + hswz(row, cb))      = hreg[r];
        *(bf16x8*)(sA + row*256 + hswz(row, cb + 16)) = hreg[4+r];
      }
    }
    // write W2 k-half (reg-staged)
#pragma unroll
    for (int i=0;i<4;i++) *(f32x4*)(sB + tid*16 + i*8192) = wbuf[i];
    __syncthreads();
    // issue loads for W2 k-half1 during GEMM2a
    if (half == 0){
#pragma unroll
      for (int i=0;i<4;i++){
        int o = tid*16 + i*8192;
        wbuf[i] = *(const f32x4*)(img2 + (o >> 8)*512 + 256 + (o & 255));
      }
    }
    // GEMM2 over this k-half
#pragma unroll
    for (int ks=0;ks<4;ks++){
      const char* ap = sA + rowA*256 + hswz(rowA, ks*64+kb0);
      bf16x8 a = *(const bf16x8*)ap;
#pragma unroll
      for (int nt=0;nt<8;nt++){
        int rn = nt*16 + (lane&15);
        bf16x8 b = lds_frag(sB, rn, 256, ks*64+kb0);
        o2[nt] = MFMA(a,b,o2[nt]);
      }
    }
    __syncthreads();
  }

  // epilogue
#pragma unroll
  for (int nt=0;nt<8;nt++){
    float s1=0.f, s2=0.f;
#pragma unroll
    for (int r=0;r<4;r++){
      int row = crow + r, col = nt*16 + ccol;
      int grow = r0 + row;
      float val = 0.f;
      if (grow < M){
        float xp = xio[(size_t)grow*DIM + col];
        float x1 = xp*ss1[col] + ss1[128+col];
        val = x1 + o2[nt][r] + b2[col];
        xio[(size_t)grow*DIM + col] = val;
      }
      s1 += val; s2 += val*val;
    }
    s1 += __shfl_xor(s1,16); s1 += __shfl_xor(s1,32);
    s2 += __shfl_xor(s2,16); s2 += __shfl_xor(s2,32);
    if (lane < 16){
      atomicAdd(&sStats[nt*16+ccol], s1);
      atomicAdd(&sStats[128+nt*16+ccol], s2);
    }
  }
  __syncthreads();
  if (tid < 256) unsafeAtomicAdd(&stats2[tid], sStats[tid]);
}

// ---------------- stats -> scale/shift ----------------
struct FinArgs { const float* st; const float* g; const float* b; float* ss; float invM; };

__global__ void k_finstats(FinArgs a0, FinArgs a1){
  FinArgs a = (blockIdx.x == 0) ? a0 : a1;
  int c = threadIdx.x;
  float mean = a.st[c] * a.invM;
  float var  = a.st[128 + c] * a.invM - mean * mean;
  float scl  = a.g[c] * rsqrtf(var + 1e-5f);
  a.ss[c] = scl;
  a.ss[128 + c] = a.b[c] - mean * scl;
}

// ---------------- in-place normalize ----------------
__global__ void k_norm(float* __restrict__ x, const float* __restrict__ ss, long long n4){
  for (long long i = (long long)blockIdx.x * blockDim.x + threadIdx.x; i < n4;
       i += (long long)gridDim.x * blockDim.x){
    float4* p = (float4*)x + i;
    float4 t = *p;
    int c0 = (int)((i * 4) & 127);
    t.x = t.x * ss[c0]     + ss[128 + c0];
    t.y = t.y * ss[c0 + 1] + ss[128 + c0 + 1];
    t.z = t.z * ss[c0 + 2] + ss[128 + c0 + 2];
    t.w = t.w * ss[c0 + 3] + ss[128 + c0 + 3];
    *p = t;
  }
}

extern "C" void kernel_launch(void* const* d_in, const int* in_sizes, int n_in,
                              void* d_out, int out_size, void* d_ws, size_t ws_size,
                              hipStream_t stream)
{
  const float* v    = (const float*)d_in[0];
  const float* e    = (const float*)d_in[1];
  const float* envl = (const float*)d_in[2];
  const int*   src  = (const int*)d_in[3];
  const int*   dst  = (const int*)d_in[4];
  const float* bOv  = (const float*)d_in[10];
  const float* bOe  = (const float*)d_in[12];
  const float* g1v  = (const float*)d_in[13];
  const float* b1vn = (const float*)d_in[14];
  const float* g1e  = (const float*)d_in[15];
  const float* b1en = (const float*)d_in[16];
  const float* g2v  = (const float*)d_in[17];
  const float* b2vn = (const float*)d_in[18];
  const float* g2e  = (const float*)d_in[19];
  const float* b2en = (const float*)d_in[20];
  const float* b1vf = (const float*)d_in[22];
  const float* b2vf = (const float*)d_in[24];
  const float* b1ef = (const float*)d_in[26];
  const float* b2ef = (const float*)d_in[28];

  float* out_v = (float*)d_out;
  float* out_e = out_v + (size_t)N_NODES * DIM;

  char* ws = (char*)d_ws;
  const size_t IMG_OFF = 0;                        // 458752 B of bf16 weight images
  const size_t QB_OFF  = 458752;                   // bf16 Q  (N*128*2 = 12.8MB)
  const size_t KB_OFF  = QB_OFF  + 12800000;       // bf16 K
  const size_t VB_OFF  = KB_OFF  + 12800000;       // bf16 V
  const size_t VA_OFF  = VB_OFF  + 12800000;       // bf16 vAttn
  const size_t SV_OFF  = VA_OFF  + 12800000;       // s per edge per head: E*8*4 = 16MB
  const size_t CSR_OFF = SV_OFF  + 16000000;       // E ints
  const size_t RP_OFF  = CSR_OFF + 2000000;        // N+1 ints
  const size_t WP_OFF  = RP_OFF  + 200016;         // N ints
  const size_t CNT_OFF = WP_OFF  + 200000;         // N ints (memset 0)
  const size_t ST_OFF  = CNT_OFF + 200000;         // 1024 f (memset 0)
  const size_t SS_OFF  = ST_OFF  + 4096;           // 1024 f

  char*   img   = ws + IMG_OFF;
  bf16_t* Qb    = (bf16_t*)(ws + QB_OFF);
  bf16_t* Kb    = (bf16_t*)(ws + KB_OFF);
  bf16_t* Vb    = (bf16_t*)(ws + VB_OFF);
  bf16_t* vAttn = (bf16_t*)(ws + VA_OFF);
  float*  svp   = (float*)(ws + SV_OFF);
  int*    csr   = (int*)(ws + CSR_OFF);
  int*    rowp  = (int*)(ws + RP_OFF);
  int*    wpp   = (int*)(ws + WP_OFF);
  int*    cnt   = (int*)(ws + CNT_OFF);
  float*  st    = (float*)(ws + ST_OFF);
  float*  ssb   = (float*)(ws + SS_OFF);
  float* st_e1 = st;        float* st_v1 = st + 256;
  float* st_v2 = st + 512;  float* st_e2 = st + 768;
  float* ss_v1 = ssb;       float* ss_e1 = ssb + 256;
  float* ss_v2 = ssb + 512; float* ss_e2 = ssb + 768;

  // zero counters + stats (contiguous)
  (void)hipMemsetAsync(ws + CNT_OFF, 0, 200000 + 4096, stream);

  WPrep wp;
  const int wid[10]   = {5,6,7,8,9,11,21,23,25,27};
  const int Ks[10]    = {128,128,128,128,128,128,128,256,128,256};
  const int Ns[10]    = {128,128,128,128,128,128,256,128,256,128};
  const int modes[10] = {0,0,0,1,0,2,3,0,3,0};   // We: n-perm; WO_e: k-perm; W1v/W1e: p16 n-perm
  int cum = 0, off = 0;
  for (int i = 0; i < 10; i++){
    wp.w[i] = (const float*)d_in[wid[i]];
    wp.Kd[i] = Ks[i]; wp.Nd[i] = Ns[i];
    wp.off[i] = off; wp.cum[i] = cum; wp.mode[i] = modes[i];
    off += Ks[i]*Ns[i]*2; cum += Ks[i]*Ns[i];
  }
  k_wprep<<<896, 256, 0, stream>>>(wp, img, cum);

  // CSR build (independent of QKV)
  k_count<<<1954, 256, 0, stream>>>(dst, cnt);
  k_scan<<<1, 1024, 0, stream>>>(cnt, rowp, wpp);
  k_fill<<<1954, 256, 0, stream>>>(dst, wpp, csr);

  k_qkv<<<391, 512, 0, stream>>>(v, img, Qb, Kb, Vb, N_NODES);

  k_edge<<<3907, 512, 0, stream>>>(e, src, dst, Qb, Kb,
                                   img + 98304 /*We*/, img + 163840 /*WO_e*/, bOe,
                                   out_e, svp, st_e1, N_EDGES);

  k_agg<<<6250, 512, 0, stream>>>(rowp, csr, src, envl, svp, Vb, vAttn, N_NODES);

  k_nodeout<<<391, 512, 0, stream>>>(vAttn, v, img + 131072 /*WO_v*/, bOv,
                                     out_v, st_v1, N_NODES);

  {
    FinArgs fv{st_v1, g1v, b1vn, ss_v1, 1.f / N_NODES};
    FinArgs fe{st_e1, g1e, b1en, ss_e1, 1.f / N_EDGES};
    k_finstats<<<2, 128, 0, stream>>>(fv, fe);
  }

  k_ffn<<<391, 512, 0, stream>>>(out_v, ss_v1, img + 196608 /*W1v*/, b1vf,
                                 img + 262144 /*W2v*/, b2vf, st_v2, N_NODES);
  k_ffn<<<3907, 512, 0, stream>>>(out_e, ss_e1, img + 327680 /*W1e*/, b1ef,
                                  img + 393216 /*W2e*/, b2ef, st_e2, N_EDGES);

  {
    FinArgs fv{st_v2, g2v, b2vn, ss_v2, 1.f / N_NODES};
    FinArgs fe{st_e2, g2e, b2en, ss_e2, 1.f / N_EDGES};
    k_finstats<<<2, 128, 0, stream>>>(fv, fe);
  }

  k_norm<<<2048, 256, 0, stream>>>(out_v, ss_v2, (long long)(N_NODES) * DIM / 4);
  k_norm<<<4096, 256, 0, stream>>>(out_e, ss_e2, (long long)(N_EDGES) * DIM / 4);
}